// Round 14
// baseline (4589.338 us; speedup 1.0000x reference)
//
#include <hip/hip_runtime.h>

#define N_NODES 100000
#define E_EDGES 1600000
#define IN_F 128
#define H_F 256
#define K_HOPS 7
#define R_REL 5
#define OUT_W (R_REL * H_F)  // 1280
#define SCAN_B ((N_NODES + 1023) / 1024)  // 98

typedef __attribute__((ext_vector_type(8))) short short8;
typedef __attribute__((ext_vector_type(4))) float f32x4;

// async global->LDS, 16B per lane; lds dest = base + lane*16
#define GLOAD16(g, l) __builtin_amdgcn_global_load_lds( \
    (const __attribute__((address_space(1))) void*)(g), \
    (__attribute__((address_space(3))) void*)(l), 16, 0, 0)

// ---------------- small utility kernels ----------------

__global__ void zero_int(int* __restrict__ p, int n) {
    int t = blockIdx.x * blockDim.x + threadIdx.x;
    if (t < n) p[t] = 0;
}

__global__ void deg_count(const int* __restrict__ row, int* __restrict__ deg) {
    int e = blockIdx.x * blockDim.x + threadIdx.x;
    if (e < E_EDGES) atomicAdd(&deg[row[e]], 1);
}

__global__ void dinv_compute(const int* __restrict__ deg, float* __restrict__ dinv) {
    int i = blockIdx.x * blockDim.x + threadIdx.x;
    if (i < N_NODES) dinv[i] = rsqrtf((float)(deg[i] + 1));
}

// ---- 3-pass exclusive scan of deg -> rowptr ----
__global__ __launch_bounds__(1024) void scan1(const int* __restrict__ deg,
                                              int* __restrict__ rp, int* __restrict__ bsum) {
    __shared__ int ws[16];
    const int t = threadIdx.x, lane = t & 63, wv = t >> 6;
    int i = blockIdx.x * 1024 + t;
    int v = (i < N_NODES) ? deg[i] : 0;
    int x = v;
#pragma unroll
    for (int off = 1; off < 64; off <<= 1) {
        int n = __shfl_up(x, off, 64);
        if (lane >= off) x += n;
    }
    if (lane == 63) ws[wv] = x;
    __syncthreads();
    if (wv == 0 && lane < 16) {
        int s = ws[lane];
#pragma unroll
        for (int off = 1; off < 16; off <<= 1) {
            int n = __shfl_up(s, off, 64);
            if (lane >= off) s += n;
        }
        ws[lane] = s;
    }
    __syncthreads();
    int wbase = (wv == 0) ? 0 : ws[wv - 1];
    if (i < N_NODES) rp[i] = wbase + x - v;
    if (t == 1023) bsum[blockIdx.x] = ws[15];
}

// parallel scan of the 98 block sums (one block, 128 threads = 2 waves)
__global__ __launch_bounds__(128) void scan2(int* __restrict__ bsum) {
    __shared__ int wtot[2];
    const int t = threadIdx.x, lane = t & 63, wv = t >> 6;
    int v = (t < SCAN_B) ? bsum[t] : 0;
    int x = v;
#pragma unroll
    for (int off = 1; off < 64; off <<= 1) {
        int n = __shfl_up(x, off, 64);
        if (lane >= off) x += n;
    }
    if (lane == 63) wtot[wv] = x;
    __syncthreads();
    int base = (wv == 1) ? wtot[0] : 0;
    if (t < SCAN_B) bsum[t] = base + x - v;
    if (t == 127) bsum[SCAN_B] = wtot[0] + wtot[1];
}

__global__ __launch_bounds__(1024) void scan3(int* __restrict__ rp,
                                              const int* __restrict__ bsum) {
    int i = blockIdx.x * 1024 + threadIdx.x;
    if (i < N_NODES) rp[i] += bsum[blockIdx.x];
    if (i == 0) rp[N_NODES] = bsum[SCAN_B];
}

__global__ void csr_scatter(const int* __restrict__ row, const int* __restrict__ col,
                            const float* __restrict__ dinv, const int* __restrict__ rowptr,
                            int* __restrict__ cursor, int* __restrict__ cols2,
                            float* __restrict__ ew) {
    int e = blockIdx.x * blockDim.x + threadIdx.x;
    if (e >= E_EDGES) return;
    int r = row[e], c = col[e];
    int pos = rowptr[r] + atomicAdd(&cursor[r], 1);
    cols2[pos] = c;
    ew[pos] = dinv[r] * dinv[c];
}

// ---------------- bf16 split helpers ----------------

__device__ __forceinline__ void f2bf_split(float v, short& h, short& l) {
    unsigned u = __float_as_uint(v);
    unsigned hb = (u + 0x7FFFu + ((u >> 16) & 1u)) >> 16;  // RN-to-even bf16
    float fh = __uint_as_float(hb << 16);
    float r = v - fh;
    unsigned u2 = __float_as_uint(r);
    unsigned lb = (u2 + 0x7FFFu + ((u2 >> 16) & 1u)) >> 16;
    h = (short)(unsigned short)hb;
    l = (short)(unsigned short)lb;
}

// ---------------- weight-fusion precompute ----------------
// Wc[z=r*3+d] = W2[r+d] @ WrS[r,d]; 8 j-rows per block via LDS A tile
__global__ __launch_bounds__(256) void wc_compute(const float* __restrict__ W2,
                                                  const float* __restrict__ Wr,
                                                  float* __restrict__ Wc) {
    __shared__ float as[8][256];
    const int z = blockIdx.x, j0 = blockIdx.y * 8, g = threadIdx.x;
    const int r = z / 3, d = z % 3, hop = r + d;
    const float* a = W2 + (size_t)hop * H_F * H_F + (size_t)j0 * H_F;
    for (int t = threadIdx.x; t < 8 * 256; t += 256)
        as[t >> 8][t & 255] = a[t];
    __syncthreads();
    const float* b = Wr + ((size_t)r * 768 + (size_t)d * H_F) * H_F + g;
    float acc[8] = {0.f, 0.f, 0.f, 0.f, 0.f, 0.f, 0.f, 0.f};
    for (int h = 0; h < H_F; ++h) {
        float bv = b[(size_t)h * H_F];
#pragma unroll
        for (int jj = 0; jj < 8; ++jj) acc[jj] += as[jj][h] * bv;
    }
#pragma unroll
    for (int jj = 0; jj < 8; ++jj)
        Wc[(size_t)z * H_F * H_F + (size_t)(j0 + jj) * H_F + g] = acc[jj];
}

// bc[r] = br[r] + sum_{d,h} b2[r+d][h] * WrS[r,d][h][:]
__global__ __launch_bounds__(256) void bc_compute(const float* __restrict__ b2,
                                                  const float* __restrict__ Wr,
                                                  const float* __restrict__ br,
                                                  float* __restrict__ bc) {
    const int r = blockIdx.x, g = threadIdx.x;
    float acc = br[(size_t)r * H_F + g];
    for (int t = 0; t < 3 * H_F; ++t) {
        float bv = b2[(size_t)(r + t / H_F) * H_F + (t % H_F)];
        acc += bv * Wr[((size_t)r * 768 + t) * H_F + g];
    }
    bc[(size_t)r * H_F + g] = acc;
}

// weight transpose+split: in [z][Kd][256] fp32 -> out group (z/grp) is [256][grp*Kd]
__global__ void transpose_convert(const float* __restrict__ in, short* __restrict__ oh,
                                  short* __restrict__ ol, int Kd, int grp) {
    __shared__ float t[32][33];
    const int i0 = blockIdx.x * 32, n0 = blockIdx.y * 32, z = blockIdx.z;
    const int tx = threadIdx.x, ty = threadIdx.y;
    const int outLd = grp * Kd;
    const float* ip = in + (size_t)z * Kd * 256;
#pragma unroll
    for (int j = 0; j < 4; ++j)
        t[ty + 8 * j][tx] = ip[(size_t)(i0 + ty + 8 * j) * 256 + n0 + tx];
    __syncthreads();
    size_t base = (size_t)(z / grp) * 256 * outLd + (size_t)(z % grp) * Kd;
#pragma unroll
    for (int j = 0; j < 4; ++j) {
        float v = t[tx][ty + 8 * j];
        short hb, lb;
        f2bf_split(v, hb, lb);
        size_t o = base + (size_t)(n0 + ty + 8 * j) * outLd + i0 + tx;
        oh[o] = hb;
        ol[o] = lb;
    }
}

// ---------------- MLP1 device body (shared by standalone + fused kernels) --------

#define LROW 40

__device__ __forceinline__ void mlp1_body(
    short* lds_buf, int midx,
    const float* __restrict__ A,
    const short* __restrict__ BTh, const short* __restrict__ BTl,
    short* __restrict__ Ch, short* __restrict__ Cl,
    const float* __restrict__ bias, int M)
{
    short* Ah = lds_buf;
    short* Al = lds_buf + 128 * LROW;
    short* Bh = lds_buf + 2 * 128 * LROW;
    short* Bl = lds_buf + 3 * 128 * LROW;

    const int tid = threadIdx.x;
    const int lane = tid & 63, wave = tid >> 6;
    const int wm = wave & 1, wn = wave >> 1;
    const int fr = lane & 15, fg = lane >> 4;
    const int m0 = (midx >> 1) * 128;
    const int n0 = (midx & 1) * 128;

    const int sr = tid >> 1;
    const int sc = (tid & 1) * 16;
    const bool avalid = (m0 + sr) < M;
    const int arow = avalid ? (m0 + sr) : (M - 1);

    f32x4 ga[4];
    short8 gbh[2], gbl[2];
    {
        const float* ap = A + (size_t)arow * IN_F + sc;
        const short* bph = BTh + (size_t)(n0 + sr) * IN_F + sc;
        const short* bpl = BTl + (size_t)(n0 + sr) * IN_F + sc;
#pragma unroll
        for (int l = 0; l < 4; ++l) ga[l] = *(const f32x4*)(ap + 4 * l);
        gbh[0] = *(const short8*)bph;  gbh[1] = *(const short8*)(bph + 8);
        gbl[0] = *(const short8*)bpl;  gbl[1] = *(const short8*)(bpl + 8);
    }

    f32x4 acc[4][4];
#pragma unroll
    for (int i = 0; i < 4; ++i)
#pragma unroll
        for (int j = 0; j < 4; ++j) acc[i][j] = (f32x4)0.f;

    const int nk = IN_F / 32;  // 4
    for (int kk = 0; kk < nk; ++kk) {
        __syncthreads();
        {
            short8 vh[2], vl[2];
#pragma unroll
            for (int l = 0; l < 4; ++l) {
                f32x4 v = ga[l];
                if (!avalid) v = (f32x4)0.f;
#pragma unroll
                for (int e = 0; e < 4; ++e) {
                    short hb, lb;
                    f2bf_split(v[e], hb, lb);
                    vh[l >> 1][(l & 1) * 4 + e] = hb;
                    vl[l >> 1][(l & 1) * 4 + e] = lb;
                }
            }
            *(short8*)(Ah + sr * LROW + sc)     = vh[0];
            *(short8*)(Ah + sr * LROW + sc + 8) = vh[1];
            *(short8*)(Al + sr * LROW + sc)     = vl[0];
            *(short8*)(Al + sr * LROW + sc + 8) = vl[1];
            *(short8*)(Bh + sr * LROW + sc)     = gbh[0];
            *(short8*)(Bh + sr * LROW + sc + 8) = gbh[1];
            *(short8*)(Bl + sr * LROW + sc)     = gbl[0];
            *(short8*)(Bl + sr * LROW + sc + 8) = gbl[1];
        }
        __syncthreads();

        if (kk + 1 < nk) {
            int k0 = (kk + 1) * 32;
            const float* ap = A + (size_t)arow * IN_F + k0 + sc;
            const short* bph = BTh + (size_t)(n0 + sr) * IN_F + k0 + sc;
            const short* bpl = BTl + (size_t)(n0 + sr) * IN_F + k0 + sc;
#pragma unroll
            for (int l = 0; l < 4; ++l) ga[l] = *(const f32x4*)(ap + 4 * l);
            gbh[0] = *(const short8*)(bph);  gbh[1] = *(const short8*)(bph + 8);
            gbl[0] = *(const short8*)(bpl);  gbl[1] = *(const short8*)(bpl + 8);
        }

        short8 afh[4], afl[4], bfh[4], bfl[4];
#pragma unroll
        for (int mf = 0; mf < 4; ++mf) {
            int r = wm * 64 + mf * 16 + fr;
            afh[mf] = *(const short8*)(Ah + r * LROW + fg * 8);
            afl[mf] = *(const short8*)(Al + r * LROW + fg * 8);
        }
#pragma unroll
        for (int nf = 0; nf < 4; ++nf) {
            int r = wn * 64 + nf * 16 + fr;
            bfh[nf] = *(const short8*)(Bh + r * LROW + fg * 8);
            bfl[nf] = *(const short8*)(Bl + r * LROW + fg * 8);
        }
#pragma unroll
        for (int mf = 0; mf < 4; ++mf)
#pragma unroll
            for (int nf = 0; nf < 4; ++nf) {
                acc[mf][nf] = __builtin_amdgcn_mfma_f32_16x16x32_bf16(
                    afh[mf], bfh[nf], acc[mf][nf], 0, 0, 0);
                acc[mf][nf] = __builtin_amdgcn_mfma_f32_16x16x32_bf16(
                    afh[mf], bfl[nf], acc[mf][nf], 0, 0, 0);
                acc[mf][nf] = __builtin_amdgcn_mfma_f32_16x16x32_bf16(
                    afl[mf], bfh[nf], acc[mf][nf], 0, 0, 0);
            }
    }

#pragma unroll
    for (int nf = 0; nf < 4; ++nf) {
        int colg = n0 + wn * 64 + nf * 16 + fr;
        float bv = bias[colg];
#pragma unroll
        for (int mf = 0; mf < 4; ++mf) {
            int rowbase = m0 + wm * 64 + mf * 16 + fg * 4;
#pragma unroll
            for (int j = 0; j < 4; ++j) {
                int rowg = rowbase + j;
                if (rowg < M) {
                    float v = fmaxf(acc[mf][nf][j] + bv, 0.f);
                    short hb, lb;
                    f2bf_split(v, hb, lb);
                    size_t idx = (size_t)rowg * H_F + colg;
                    Ch[idx] = hb;
                    Cl[idx] = lb;
                }
            }
        }
    }
}

// ---------------- spmm device body ----------------
// y[i] = dinv[i]^2 * x[i] + sum_j w[j] * x[cols[j]]
// one wave per row; 2 edge slots x 32 lanes x float4; 4-deep unroll per slot
__device__ __forceinline__ void spmm_body(
    int i,
    const float4* __restrict__ x, const int* __restrict__ rowptr,
    const int* __restrict__ cols, const float* __restrict__ w,
    const float* __restrict__ dinv, float4* __restrict__ y)
{
    const int lane = threadIdx.x & 63;
    const int fh = lane & 31;
    const int slot = lane >> 5;
    const int jb = rowptr[i];
    const int cnt = rowptr[i + 1] - jb;

    float4 acc = make_float4(0.f, 0.f, 0.f, 0.f);
    int t = slot;
    for (; t + 6 < cnt; t += 8) {
        int c0 = cols[jb + t],     c1 = cols[jb + t + 2];
        int c2 = cols[jb + t + 4], c3 = cols[jb + t + 6];
        float ww0 = w[jb + t],     ww1 = w[jb + t + 2];
        float ww2 = w[jb + t + 4], ww3 = w[jb + t + 6];
        float4 v0 = x[(size_t)c0 * 32 + fh];
        float4 v1 = x[(size_t)c1 * 32 + fh];
        float4 v2 = x[(size_t)c2 * 32 + fh];
        float4 v3 = x[(size_t)c3 * 32 + fh];
        acc.x += ww0 * v0.x + ww1 * v1.x + ww2 * v2.x + ww3 * v3.x;
        acc.y += ww0 * v0.y + ww1 * v1.y + ww2 * v2.y + ww3 * v3.y;
        acc.z += ww0 * v0.z + ww1 * v1.z + ww2 * v2.z + ww3 * v3.z;
        acc.w += ww0 * v0.w + ww1 * v1.w + ww2 * v2.w + ww3 * v3.w;
    }
    for (; t < cnt; t += 2) {
        int c0 = cols[jb + t];
        float ww0 = w[jb + t];
        float4 v0 = x[(size_t)c0 * 32 + fh];
        acc.x += ww0 * v0.x;
        acc.y += ww0 * v0.y;
        acc.z += ww0 * v0.z;
        acc.w += ww0 * v0.w;
    }
    acc.x += __shfl_xor(acc.x, 32);
    acc.y += __shfl_xor(acc.y, 32);
    acc.z += __shfl_xor(acc.z, 32);
    acc.w += __shfl_xor(acc.w, 32);
    if (slot == 0) {
        float d = dinv[i];
        float s = d * d;
        float4 xv = x[(size_t)i * 32 + fh];
        acc.x += s * xv.x;
        acc.y += s * xv.y;
        acc.z += s * xv.z;
        acc.w += s * xv.w;
        y[(size_t)i * 32 + fh] = acc;
    }
}

// ---------------- standalone kernels ----------------

__global__ __launch_bounds__(256, 2) void gemm_mlp(
    const float* __restrict__ A,
    const short* __restrict__ BTh, const short* __restrict__ BTl,
    short* __restrict__ Ch, short* __restrict__ Cl,
    const float* __restrict__ bias, int M)
{
    __shared__ short lds_buf[4 * 128 * LROW];
    mlp1_body(lds_buf, blockIdx.x, A, BTh, BTl, Ch, Cl, bias, M);
}

__global__ __launch_bounds__(256) void spmm_csr(
    const float4* __restrict__ x, const int* __restrict__ rowptr,
    const int* __restrict__ cols, const float* __restrict__ w,
    const float* __restrict__ dinv, float4* __restrict__ y) {
    const int i = blockIdx.x * 4 + (threadIdx.x >> 6);
    if (i < N_NODES) spmm_body(i, x, rowptr, cols, w, dinv, y);
}

// ---------------- fused MLP1 + spmm (independent work, co-scheduled) ----------
// Both only READ xcur; MLP1 writes h1[k], spmm writes x_{k+1} -- disjoint.
// MLP blocks interleaved every 16th block so both populations stay co-resident.

__global__ __launch_bounds__(256, 4) void mlp_spmm(
    const float* __restrict__ xcur,
    const short* __restrict__ BTh, const short* __restrict__ BTl,
    short* __restrict__ Ch, short* __restrict__ Cl,
    const float* __restrict__ bias,
    const int* __restrict__ rowptr, const int* __restrict__ cols,
    const float* __restrict__ w, const float* __restrict__ dinv,
    float4* __restrict__ y, int nm)
{
    __shared__ short lds_buf[4 * 128 * LROW];
    const int bid = blockIdx.x;
    const int thresh = nm * 16;
    if (bid < thresh && (bid & 15) == 0) {
        mlp1_body(lds_buf, bid >> 4, xcur, BTh, BTl, Ch, Cl, bias, N_NODES);
    } else {
        int sidx = (bid < thresh) ? (bid - (bid >> 4) - 1) : (bid - nm);
        int i = sidx * 4 + (threadIdx.x >> 6);
        if (i < N_NODES)
            spmm_body(i, (const float4*)xcur, rowptr, cols, w, dinv, y);
    }
}

// ---------------- relation GEMM v5: 256x256 tile, 8 waves, counted-vmcnt dbuf -----
// (unchanged from round 13)

__global__ __launch_bounds__(512, 2) void gemm_rel(
    const short* __restrict__ h1h, const short* __restrict__ h1l, long hopStride,
    const short* __restrict__ wch, const short* __restrict__ wcl,
    float* __restrict__ outB, const float* __restrict__ bcB, int M, int nwg)
{
    __shared__ short lds[2][4][8192];  // Ah, Al, Bh, Bl: 256 rows x 32 k each

    // bijective XCD swizzle (m204)
    const int bid = blockIdx.x;
    const int q8 = nwg >> 3, r8 = nwg & 7;
    const int xcd = bid & 7, idx = bid >> 3;
    const int wgid = (xcd < r8) ? (xcd * (q8 + 1) + idx)
                                : (r8 * (q8 + 1) + (xcd - r8) * q8 + idx);
    const int rrel = wgid % R_REL;     // relation fastest -> A m-panel L2-shared
    const int mblk = wgid / R_REL;
    const int m0 = mblk * 256;

    const int tid = threadIdx.x;
    const int lane = tid & 63, wave = tid >> 6;  // 8 waves
    const int wm = wave & 1, wn = wave >> 1;     // 2M x 4N
    const int fr = lane & 15, fg = lane >> 4;

    const short* Agh = h1h + (size_t)rrel * hopStride;
    const short* Agl = h1l + (size_t)rrel * hopStride;
    const short* BTh = wch + (size_t)rrel * 256 * 768;
    const short* BTl = wcl + (size_t)rrel * 256 * 768;
    float* C = outB + (size_t)rrel * H_F;
    const float* bias = bcB + (size_t)rrel * H_F;

    // hop-phase rotation start (in k-steps of 32): r=0..4 -> 0,16,8,0,16
    const int kstart = ((3 - (rrel % 3)) % 3) * 8;

    // staging offsets: call c = wave*2+p covers rows c*16..c*16+15 of a 256-row plane
    int aoff[2], boff[2], loff[2];
#pragma unroll
    for (int p = 0; p < 2; ++p) {
        int c = wave * 2 + p;
        int r = c * 16 + (lane >> 2);
        int u = lane & 3;
        int g = (u - (r >> 1)) & 3;
        int ar = m0 + r; if (ar >= M) ar = M - 1;
        aoff[p] = ar * H_F + g * 8;        // A row stride 256 shorts
        boff[p] = r * 768 + g * 8;         // B row stride 768 shorts (n0 = 0)
        loff[p] = c * 512;                 // 1KB per wave-call
    }

#define STAGE_REL(buf, kg) do {                                                  \
        int hop_ = (kg) >> 8, kin_ = (kg) & 255;                                 \
        const short* ah_ = Agh + (size_t)hop_ * hopStride + kin_;                \
        const short* al_ = Agl + (size_t)hop_ * hopStride + kin_;                \
        const short* bh_ = BTh + (kg);                                           \
        const short* bl_ = BTl + (kg);                                           \
        GLOAD16(ah_ + aoff[0], &lds[buf][0][loff[0]]);                           \
        GLOAD16(ah_ + aoff[1], &lds[buf][0][loff[1]]);                           \
        GLOAD16(al_ + aoff[0], &lds[buf][1][loff[0]]);                           \
        GLOAD16(al_ + aoff[1], &lds[buf][1][loff[1]]);                           \
        GLOAD16(bh_ + boff[0], &lds[buf][2][loff[0]]);                           \
        GLOAD16(bh_ + boff[1], &lds[buf][2][loff[1]]);                           \
        GLOAD16(bl_ + boff[0], &lds[buf][3][loff[0]]);                           \
        GLOAD16(bl_ + boff[1], &lds[buf][3][loff[1]]);                           \
    } while (0)

#define KIDX(t) ((((t) + kstart) % nk) * 32)

    f32x4 acc[8][4];
#pragma unroll
    for (int i = 0; i < 8; ++i)
#pragma unroll
        for (int j = 0; j < 4; ++j) acc[i][j] = (f32x4)0.f;

    const int nk = 768 / 32;  // 24

    // prologue: fill both buffers; 16 loads in flight per wave
    STAGE_REL(0, KIDX(0));
    STAGE_REL(1, KIDX(1));

    int cur = 0;
    for (int kt = 0; kt < nk; ++kt) {
        // wait for buf[cur]'s 8 loads; leave the next tile's 8 in flight (T4)
        if (kt + 1 < nk) {
            asm volatile("s_waitcnt vmcnt(8)" ::: "memory");
        } else {
            asm volatile("s_waitcnt vmcnt(0)" ::: "memory");
        }
        __builtin_amdgcn_sched_barrier(0);
        __builtin_amdgcn_s_barrier();          // all waves' buf[cur] data published
        __builtin_amdgcn_sched_barrier(0);

        const short* Ahc = &lds[cur][0][0];
        const short* Alc = &lds[cur][1][0];
        const short* Bhc = &lds[cur][2][0];
        const short* Blc = &lds[cur][3][0];

        short8 bfh[4], bfl[4];
#pragma unroll
        for (int nf = 0; nf < 4; ++nf) {
            int rb = wn * 64 + nf * 16 + fr;
            int ub = (fg + (rb >> 1)) & 3;
            bfh[nf] = *(const short8*)(Bhc + rb * 32 + ub * 8);
            bfl[nf] = *(const short8*)(Blc + rb * 32 + ub * 8);
        }
        __builtin_amdgcn_s_setprio(1);
#pragma unroll
        for (int mf = 0; mf < 8; ++mf) {
            int ra = wm * 128 + mf * 16 + fr;
            int ua = (fg + (ra >> 1)) & 3;
            short8 ah = *(const short8*)(Ahc + ra * 32 + ua * 8);
            short8 al = *(const short8*)(Alc + ra * 32 + ua * 8);
#pragma unroll
            for (int nf = 0; nf < 4; ++nf) {
                acc[mf][nf] = __builtin_amdgcn_mfma_f32_16x16x32_bf16(
                    ah, bfh[nf], acc[mf][nf], 0, 0, 0);
                acc[mf][nf] = __builtin_amdgcn_mfma_f32_16x16x32_bf16(
                    ah, bfl[nf], acc[mf][nf], 0, 0, 0);
                acc[mf][nf] = __builtin_amdgcn_mfma_f32_16x16x32_bf16(
                    al, bfh[nf], acc[mf][nf], 0, 0, 0);
            }
        }
        __builtin_amdgcn_s_setprio(0);

        __builtin_amdgcn_sched_barrier(0);
        __builtin_amdgcn_s_barrier();          // all waves' reads of buf[cur] done
        __builtin_amdgcn_sched_barrier(0);

        if (kt + 2 < nk) STAGE_REL(cur, KIDX(kt + 2));  // overwrite now safe
        cur ^= 1;
    }

#pragma unroll
    for (int nf = 0; nf < 4; ++nf) {
        int colg = wn * 64 + nf * 16 + fr;     // n0 = 0
        float bv = bias[colg];
#pragma unroll
        for (int mf = 0; mf < 8; ++mf) {
            int rowbase = m0 + wm * 128 + mf * 16 + fg * 4;
#pragma unroll
            for (int j = 0; j < 4; ++j) {
                int rowg = rowbase + j;
                if (rowg < M)
                    C[(size_t)rowg * OUT_W + colg] = fmaxf(acc[mf][nf][j] + bv, 0.f);
            }
        }
    }
#undef STAGE_REL
#undef KIDX
}

// ---------------- fallback relation GEMM (pre-split A, reg-staged) ----------------
// MODE: 0 = bias, 2 = accum, 3 = accum+relu   (non-windowed path only)

template <int MODE>
__global__ __launch_bounds__(256, 2) void gemm_presplit(
    const short* __restrict__ Agh, const short* __restrict__ Agl, int lda,
    const short* __restrict__ BTh, const short* __restrict__ BTl, int ldb, int Kd,
    float* __restrict__ C, int ldc, const float* __restrict__ bias, int M)
{
    __shared__ short lds_buf[4 * 128 * LROW];
    short* Ah = lds_buf;
    short* Al = lds_buf + 128 * LROW;
    short* Bh = lds_buf + 2 * 128 * LROW;
    short* Bl = lds_buf + 3 * 128 * LROW;

    const int tid = threadIdx.x;
    const int lane = tid & 63, wave = tid >> 6;
    const int wm = wave & 1, wn = wave >> 1;
    const int fr = lane & 15, fg = lane >> 4;
    const int m0 = blockIdx.y * 128;
    const int n0 = blockIdx.x * 128;

    const int sr = tid >> 1;
    const int sc = (tid & 1) * 16;
    const bool avalid = (m0 + sr) < M;
    const int arow = avalid ? (m0 + sr) : (M - 1);

    short8 gah[2], gal[2], gbh[2], gbl[2];
    {
        const short* aph = Agh + (size_t)arow * lda + sc;
        const short* apl = Agl + (size_t)arow * lda + sc;
        const short* bph = BTh + (size_t)(n0 + sr) * ldb + sc;
        const short* bpl = BTl + (size_t)(n0 + sr) * ldb + sc;
        gah[0] = *(const short8*)aph;  gah[1] = *(const short8*)(aph + 8);
        gal[0] = *(const short8*)apl;  gal[1] = *(const short8*)(apl + 8);
        gbh[0] = *(const short8*)bph;  gbh[1] = *(const short8*)(bph + 8);
        gbl[0] = *(const short8*)bpl;  gbl[1] = *(const short8*)(bpl + 8);
    }

    f32x4 acc[4][4];
#pragma unroll
    for (int i = 0; i < 4; ++i)
#pragma unroll
        for (int j = 0; j < 4; ++j) acc[i][j] = (f32x4)0.f;

    const int nk = Kd / 32;
    for (int kk = 0; kk < nk; ++kk) {
        __syncthreads();
        *(short8*)(Ah + sr * LROW + sc)     = gah[0];
        *(short8*)(Ah + sr * LROW + sc + 8) = gah[1];
        *(short8*)(Al + sr * LROW + sc)     = gal[0];
        *(short8*)(Al + sr * LROW + sc + 8) = gal[1];
        *(short8*)(Bh + sr * LROW + sc)     = gbh[0];
        *(short8*)(Bh + sr * LROW + sc + 8) = gbh[1];
        *(short8*)(Bl + sr * LROW + sc)     = gbl[0];
        *(short8*)(Bl + sr * LROW + sc + 8) = gbl[1];
        __syncthreads();

        if (kk + 1 < nk) {
            int k0 = (kk + 1) * 32;
            const short* aph = Agh + (size_t)arow * lda + k0 + sc;
            const short* apl = Agl + (size_t)arow * lda + k0 + sc;
            const short* bph = BTh + (size_t)(n0 + sr) * ldb + k0 + sc;
            const short* bpl = BTl + (size_t)(n0 + sr) * ldb + k0 + sc;
            gah[0] = *(const short8*)aph;  gah[1] = *(const short8*)(aph + 8);
            gal[0] = *(const short8*)apl;  gal[1] = *(const short8*)(apl + 8);
            gbh[0] = *(const short8*)bph;  gbh[1] = *(const short8*)(bph + 8);
            gbl[0] = *(const short8*)bpl;  gbl[1] = *(const short8*)(bpl + 8);
        }

        short8 afh[4], afl[4], bfh[4], bfl[4];
#pragma unroll
        for (int mf = 0; mf < 4; ++mf) {
            int r = wm * 64 + mf * 16 + fr;
            afh[mf] = *(const short8*)(Ah + r * LROW + fg * 8);
            afl[mf] = *(const short8*)(Al + r * LROW + fg * 8);
        }
#pragma unroll
        for (int nf = 0; nf < 4; ++nf) {
            int r = wn * 64 + nf * 16 + fr;
            bfh[nf] = *(const short8*)(Bh + r * LROW + fg * 8);
            bfl[nf] = *(const short8*)(Bl + r * LROW + fg * 8);
        }
#pragma unroll
        for (int mf = 0; mf < 4; ++mf)
#pragma unroll
            for (int nf = 0; nf < 4; ++nf) {
                acc[mf][nf] = __builtin_amdgcn_mfma_f32_16x16x32_bf16(
                    afh[mf], bfh[nf], acc[mf][nf], 0, 0, 0);
                acc[mf][nf] = __builtin_amdgcn_mfma_f32_16x16x32_bf16(
                    afh[mf], bfl[nf], acc[mf][nf], 0, 0, 0);
                acc[mf][nf] = __builtin_amdgcn_mfma_f32_16x16x32_bf16(
                    afl[mf], bfh[nf], acc[mf][nf], 0, 0, 0);
            }
    }

#pragma unroll
    for (int nf = 0; nf < 4; ++nf) {
        int colg = n0 + wn * 64 + nf * 16 + fr;
        float bv = (MODE == 0) ? bias[colg] : 0.f;
#pragma unroll
        for (int mf = 0; mf < 4; ++mf) {
            int rowbase = m0 + wm * 64 + mf * 16 + fg * 4;
#pragma unroll
            for (int j = 0; j < 4; ++j) {
                int rowg = rowbase + j;
                if (rowg < M) {
                    size_t idx = (size_t)rowg * ldc + colg;
                    float v = acc[mf][nf][j] + bv;
                    if (MODE >= 2) v += C[idx];
                    if (MODE & 1) v = fmaxf(v, 0.f);
                    C[idx] = v;
                }
            }
        }
    }
}

// ---------------- driver ----------------

extern "C" void kernel_launch(void* const* d_in, const int* in_sizes, int n_in,
                              void* d_out, int out_size, void* d_ws, size_t ws_size,
                              hipStream_t stream) {
    const float* features = (const float*)d_in[0];
    const float* W1 = (const float*)d_in[1];
    const float* b1 = (const float*)d_in[2];
    const float* W2 = (const float*)d_in[3];
    const float* b2 = (const float*)d_in[4];
    const float* Wr = (const float*)d_in[5];
    const float* br = (const float*)d_in[6];
    const int* row = (const int*)d_in[7];
    const int* col = (const int*)d_in[8];
    float* out = (float*)d_out;

    // workspace layout (byte offsets; ws_size ~1953 MiB)
    char* ws = (char*)d_ws;
    int* deg = (int*)ws;                                 // 400KB (also cursor)
    int* rowptr = (int*)(ws + (1ull << 20));
    float* dinv = (float*)(ws + (2ull << 20));
    int* bsum = (int*)(ws + (3ull << 20));               // SCAN_B+1 ints
    int* cols2 = (int*)(ws + (4ull << 20));              // 6.4MB
    float* ew = (float*)(ws + (11ull << 20));            // 6.4MB
    short* w1h = (short*)(ws + (18ull << 20));           // 459KB
    short* w1l = (short*)(ws + (19ull << 20));
    float* wc32 = (float*)(ws + (20ull << 20));          // 3.93MB
    short* wch = (short*)(ws + (24ull << 20));           // 1.97MB
    short* wcl = (short*)(ws + (26ull << 20));
    float* bc = (float*)(ws + (28ull << 20));            // 5KB
    float* xa = (float*)(ws + (32ull << 20));            // 51.2MB
    float* xb = (float*)(ws + (96ull << 20));            // 51.2MB
    short* h1h = (short*)(ws + (160ull << 20));          // 341.8MiB (windowed)
    short* h1l = (short*)(ws + (576ull << 20));          // 341.8MiB

    const bool windowed = ws_size >= (1000ull << 20);

    // ---- adjacency normalization + CSR build ----
    zero_int<<<(N_NODES + 255) / 256, 256, 0, stream>>>(deg, N_NODES);
    deg_count<<<(E_EDGES + 255) / 256, 256, 0, stream>>>(row, deg);
    dinv_compute<<<(N_NODES + 255) / 256, 256, 0, stream>>>(deg, dinv);
    scan1<<<SCAN_B, 1024, 0, stream>>>(deg, rowptr, bsum);
    scan2<<<1, 128, 0, stream>>>(bsum);
    scan3<<<SCAN_B, 1024, 0, stream>>>(rowptr, bsum);
    zero_int<<<(N_NODES + 255) / 256, 256, 0, stream>>>(deg, N_NODES);
    csr_scatter<<<(E_EDGES + 255) / 256, 256, 0, stream>>>(row, col, dinv, rowptr,
                                                           deg, cols2, ew);

    // ---- weight fusion: Wc = W2 @ WrS, bc = br + b2 @ WrS ----
    wc_compute<<<dim3(15, 32), 256, 0, stream>>>(W2, Wr, wc32);
    bc_compute<<<R_REL, 256, 0, stream>>>(b2, Wr, br, bc);

    // ---- weight transpose + bf16 split ----
    dim3 tb(32, 8);
    transpose_convert<<<dim3(IN_F / 32, 8, K_HOPS), tb, 0, stream>>>(W1, w1h, w1l, IN_F, 1);
    transpose_convert<<<dim3(H_F / 32, 8, 15), tb, 0, stream>>>(wc32, wch, wcl, H_F, 3);

    // ---- hop loop ----
    const float* xcur = features;
    float* bufs[2] = {xa, xb};
    const int nm = 2 * ((N_NODES + 127) / 128);   // 1564 MLP tiles
    const int ns = (N_NODES + 3) / 4;             // 25000 spmm blocks
    for (int k = 0; k < K_HOPS; ++k) {
        short* h1hd = windowed ? (h1h + (size_t)k * N_NODES * H_F) : h1h;
        short* h1ld = windowed ? (h1l + (size_t)k * N_NODES * H_F) : h1l;

        if (windowed && k < K_HOPS - 1) {
            // fused: MLP1(k) + spmm(k -> k+1), both read xcur only
            float* xn = bufs[k & 1];
            mlp_spmm<<<nm + ns, 256, 0, stream>>>(
                xcur, w1h + (size_t)k * 256 * IN_F, w1l + (size_t)k * 256 * IN_F,
                h1hd, h1ld, b1 + (size_t)k * H_F,
                rowptr, cols2, ew, dinv, (float4*)xn, nm);
            xcur = xn;
        } else {
            dim3 grid(2, (N_NODES + 127) / 128);
            gemm_mlp<<<dim3(nm), 256, 0, stream>>>(
                xcur, w1h + (size_t)k * 256 * IN_F, w1l + (size_t)k * 256 * IN_F,
                h1hd, h1ld, b1 + (size_t)k * H_F, N_NODES);

            if (!windowed) {
                int rlo = (k - 2 < 0) ? 0 : (k - 2);
                int rhi = (k < R_REL - 1) ? k : (R_REL - 1);
                for (int r = rlo; r <= rhi; ++r) {
                    int d = k - r;
                    const short* Bh = wch + (size_t)r * 256 * 768 + (size_t)d * H_F;
                    const short* Bl = wcl + (size_t)r * 256 * 768 + (size_t)d * H_F;
                    float* Cp = out + (size_t)r * H_F;
                    if (k == r)
                        gemm_presplit<0><<<grid, 256, 0, stream>>>(
                            h1h, h1l, H_F, Bh, Bl, 768, H_F, Cp, OUT_W,
                            bc + (size_t)r * H_F, N_NODES);
                    else if (k == r + 2)
                        gemm_presplit<3><<<grid, 256, 0, stream>>>(
                            h1h, h1l, H_F, Bh, Bl, 768, H_F, Cp, OUT_W, nullptr, N_NODES);
                    else
                        gemm_presplit<2><<<grid, 256, 0, stream>>>(
                            h1h, h1l, H_F, Bh, Bl, 768, H_F, Cp, OUT_W, nullptr, N_NODES);
                }
                if (k < K_HOPS - 1) {
                    float* xn = bufs[k & 1];
                    spmm_csr<<<ns, 256, 0, stream>>>(
                        (const float4*)xcur, rowptr, cols2, ew, dinv, (float4*)xn);
                    xcur = xn;
                }
            }
        }
    }

    if (windowed) {
        // all 5 relation GEMMs in one 1D launch; 256x256 tiles, rel-fastest decode
        int mblocks = (N_NODES + 255) / 256;
        int nwg = mblocks * R_REL;
        gemm_rel<<<nwg, 512, 0, stream>>>(h1h, h1l, (long)N_NODES * H_F,
                                          wch, wcl, out, bc, N_NODES, nwg);
    }
}

// Round 15
// 2174.982 us; speedup vs baseline: 2.1101x; 2.1101x over previous
//
#include <hip/hip_runtime.h>

#define N_NODES 100000
#define E_EDGES 1600000
#define IN_F 128
#define H_F 256
#define K_HOPS 7
#define R_REL 5
#define OUT_W (R_REL * H_F)  // 1280
#define SCAN_B ((N_NODES + 1023) / 1024)  // 98

typedef __attribute__((ext_vector_type(8))) short short8;
typedef __attribute__((ext_vector_type(4))) float f32x4;

// async global->LDS, 16B per lane; lds dest = base + lane*16
#define GLOAD16(g, l) __builtin_amdgcn_global_load_lds( \
    (const __attribute__((address_space(1))) void*)(g), \
    (__attribute__((address_space(3))) void*)(l), 16, 0, 0)

// ---------------- small utility kernels ----------------

__global__ void zero_int(int* __restrict__ p, int n) {
    int t = blockIdx.x * blockDim.x + threadIdx.x;
    if (t < n) p[t] = 0;
}

__global__ void deg_count(const int* __restrict__ row, int* __restrict__ deg) {
    int e = blockIdx.x * blockDim.x + threadIdx.x;
    if (e < E_EDGES) atomicAdd(&deg[row[e]], 1);
}

__global__ void dinv_compute(const int* __restrict__ deg, float* __restrict__ dinv) {
    int i = blockIdx.x * blockDim.x + threadIdx.x;
    if (i < N_NODES) dinv[i] = rsqrtf((float)(deg[i] + 1));
}

// ---- 3-pass exclusive scan of deg -> rowptr ----
__global__ __launch_bounds__(1024) void scan1(const int* __restrict__ deg,
                                              int* __restrict__ rp, int* __restrict__ bsum) {
    __shared__ int ws[16];
    const int t = threadIdx.x, lane = t & 63, wv = t >> 6;
    int i = blockIdx.x * 1024 + t;
    int v = (i < N_NODES) ? deg[i] : 0;
    int x = v;
#pragma unroll
    for (int off = 1; off < 64; off <<= 1) {
        int n = __shfl_up(x, off, 64);
        if (lane >= off) x += n;
    }
    if (lane == 63) ws[wv] = x;
    __syncthreads();
    if (wv == 0 && lane < 16) {
        int s = ws[lane];
#pragma unroll
        for (int off = 1; off < 16; off <<= 1) {
            int n = __shfl_up(s, off, 64);
            if (lane >= off) s += n;
        }
        ws[lane] = s;
    }
    __syncthreads();
    int wbase = (wv == 0) ? 0 : ws[wv - 1];
    if (i < N_NODES) rp[i] = wbase + x - v;
    if (t == 1023) bsum[blockIdx.x] = ws[15];
}

// parallel scan of the 98 block sums (one block, 128 threads = 2 waves)
__global__ __launch_bounds__(128) void scan2(int* __restrict__ bsum) {
    __shared__ int wtot[2];
    const int t = threadIdx.x, lane = t & 63, wv = t >> 6;
    int v = (t < SCAN_B) ? bsum[t] : 0;
    int x = v;
#pragma unroll
    for (int off = 1; off < 64; off <<= 1) {
        int n = __shfl_up(x, off, 64);
        if (lane >= off) x += n;
    }
    if (lane == 63) wtot[wv] = x;
    __syncthreads();
    int base = (wv == 1) ? wtot[0] : 0;
    if (t < SCAN_B) bsum[t] = base + x - v;
    if (t == 127) bsum[SCAN_B] = wtot[0] + wtot[1];
}

__global__ __launch_bounds__(1024) void scan3(int* __restrict__ rp,
                                              const int* __restrict__ bsum) {
    int i = blockIdx.x * 1024 + threadIdx.x;
    if (i < N_NODES) rp[i] += bsum[blockIdx.x];
    if (i == 0) rp[N_NODES] = bsum[SCAN_B];
}

__global__ void csr_scatter(const int* __restrict__ row, const int* __restrict__ col,
                            const float* __restrict__ dinv, const int* __restrict__ rowptr,
                            int* __restrict__ cursor, int* __restrict__ cols2,
                            float* __restrict__ ew) {
    int e = blockIdx.x * blockDim.x + threadIdx.x;
    if (e >= E_EDGES) return;
    int r = row[e], c = col[e];
    int pos = rowptr[r] + atomicAdd(&cursor[r], 1);
    cols2[pos] = c;
    ew[pos] = dinv[r] * dinv[c];
}

// y[i] = dinv[i]^2 * x[i] + sum_j w[j] * x[cols[j]]
// one wave per row; 2 edge slots x 32 lanes x float4; 4-deep unroll per slot
__global__ __launch_bounds__(256) void spmm_csr(
    const float4* __restrict__ x, const int* __restrict__ rowptr,
    const int* __restrict__ cols, const float* __restrict__ w,
    const float* __restrict__ dinv, float4* __restrict__ y) {
    const int wave = threadIdx.x >> 6, lane = threadIdx.x & 63;
    const int i = blockIdx.x * 4 + wave;
    if (i >= N_NODES) return;
    const int fh = lane & 31;
    const int slot = lane >> 5;
    const int jb = rowptr[i];
    const int cnt = rowptr[i + 1] - jb;

    float4 acc = make_float4(0.f, 0.f, 0.f, 0.f);
    int t = slot;
    for (; t + 6 < cnt; t += 8) {
        int c0 = cols[jb + t],     c1 = cols[jb + t + 2];
        int c2 = cols[jb + t + 4], c3 = cols[jb + t + 6];
        float ww0 = w[jb + t],     ww1 = w[jb + t + 2];
        float ww2 = w[jb + t + 4], ww3 = w[jb + t + 6];
        float4 v0 = x[(size_t)c0 * 32 + fh];
        float4 v1 = x[(size_t)c1 * 32 + fh];
        float4 v2 = x[(size_t)c2 * 32 + fh];
        float4 v3 = x[(size_t)c3 * 32 + fh];
        acc.x += ww0 * v0.x + ww1 * v1.x + ww2 * v2.x + ww3 * v3.x;
        acc.y += ww0 * v0.y + ww1 * v1.y + ww2 * v2.y + ww3 * v3.y;
        acc.z += ww0 * v0.z + ww1 * v1.z + ww2 * v2.z + ww3 * v3.z;
        acc.w += ww0 * v0.w + ww1 * v1.w + ww2 * v2.w + ww3 * v3.w;
    }
    for (; t < cnt; t += 2) {
        int c0 = cols[jb + t];
        float ww0 = w[jb + t];
        float4 v0 = x[(size_t)c0 * 32 + fh];
        acc.x += ww0 * v0.x;
        acc.y += ww0 * v0.y;
        acc.z += ww0 * v0.z;
        acc.w += ww0 * v0.w;
    }
    acc.x += __shfl_xor(acc.x, 32);
    acc.y += __shfl_xor(acc.y, 32);
    acc.z += __shfl_xor(acc.z, 32);
    acc.w += __shfl_xor(acc.w, 32);
    if (slot == 0) {
        float d = dinv[i];
        float s = d * d;
        float4 xv = x[(size_t)i * 32 + fh];
        acc.x += s * xv.x;
        acc.y += s * xv.y;
        acc.z += s * xv.z;
        acc.w += s * xv.w;
        y[(size_t)i * 32 + fh] = acc;
    }
}

// ---------------- bf16 split helpers ----------------

__device__ __forceinline__ void f2bf_split(float v, short& h, short& l) {
    unsigned u = __float_as_uint(v);
    unsigned hb = (u + 0x7FFFu + ((u >> 16) & 1u)) >> 16;  // RN-to-even bf16
    float fh = __uint_as_float(hb << 16);
    float r = v - fh;
    unsigned u2 = __float_as_uint(r);
    unsigned lb = (u2 + 0x7FFFu + ((u2 >> 16) & 1u)) >> 16;
    h = (short)(unsigned short)hb;
    l = (short)(unsigned short)lb;
}

// ---------------- weight-fusion precompute ----------------
// Wc[z=r*3+d] = W2[r+d] @ WrS[r,d]; 8 j-rows per block via LDS A tile
__global__ __launch_bounds__(256) void wc_compute(const float* __restrict__ W2,
                                                  const float* __restrict__ Wr,
                                                  float* __restrict__ Wc) {
    __shared__ float as[8][256];
    const int z = blockIdx.x, j0 = blockIdx.y * 8, g = threadIdx.x;
    const int r = z / 3, d = z % 3, hop = r + d;
    const float* a = W2 + (size_t)hop * H_F * H_F + (size_t)j0 * H_F;
    for (int t = threadIdx.x; t < 8 * 256; t += 256)
        as[t >> 8][t & 255] = a[t];
    __syncthreads();
    const float* b = Wr + ((size_t)r * 768 + (size_t)d * H_F) * H_F + g;
    float acc[8] = {0.f, 0.f, 0.f, 0.f, 0.f, 0.f, 0.f, 0.f};
    for (int h = 0; h < H_F; ++h) {
        float bv = b[(size_t)h * H_F];
#pragma unroll
        for (int jj = 0; jj < 8; ++jj) acc[jj] += as[jj][h] * bv;
    }
#pragma unroll
    for (int jj = 0; jj < 8; ++jj)
        Wc[(size_t)z * H_F * H_F + (size_t)(j0 + jj) * H_F + g] = acc[jj];
}

// bc[r] = br[r] + sum_{d,h} b2[r+d][h] * WrS[r,d][h][:]
__global__ __launch_bounds__(256) void bc_compute(const float* __restrict__ b2,
                                                  const float* __restrict__ Wr,
                                                  const float* __restrict__ br,
                                                  float* __restrict__ bc) {
    const int r = blockIdx.x, g = threadIdx.x;
    float acc = br[(size_t)r * H_F + g];
    for (int t = 0; t < 3 * H_F; ++t) {
        float bv = b2[(size_t)(r + t / H_F) * H_F + (t % H_F)];
        acc += bv * Wr[((size_t)r * 768 + t) * H_F + g];
    }
    bc[(size_t)r * H_F + g] = acc;
}

// weight transpose+split: in [z][Kd][256] fp32 -> out group (z/grp) is [256][grp*Kd]
__global__ void transpose_convert(const float* __restrict__ in, short* __restrict__ oh,
                                  short* __restrict__ ol, int Kd, int grp) {
    __shared__ float t[32][33];
    const int i0 = blockIdx.x * 32, n0 = blockIdx.y * 32, z = blockIdx.z;
    const int tx = threadIdx.x, ty = threadIdx.y;
    const int outLd = grp * Kd;
    const float* ip = in + (size_t)z * Kd * 256;
#pragma unroll
    for (int j = 0; j < 4; ++j)
        t[ty + 8 * j][tx] = ip[(size_t)(i0 + ty + 8 * j) * 256 + n0 + tx];
    __syncthreads();
    size_t base = (size_t)(z / grp) * 256 * outLd + (size_t)(z % grp) * Kd;
#pragma unroll
    for (int j = 0; j < 4; ++j) {
        float v = t[tx][ty + 8 * j];
        short hb, lb;
        f2bf_split(v, hb, lb);
        size_t o = base + (size_t)(n0 + ty + 8 * j) * outLd + i0 + tx;
        oh[o] = hb;
        ol[o] = lb;
    }
}

// ---------------- MLP1 GEMM: fp32 A, in-kernel split, split-bf16 output ----------------
// Ch/Cl[M,256] = relu(A[M,128] @ B[128,256] + bias), reg-staged, LROW=40 pad

#define LROW 40

__global__ __launch_bounds__(256, 2) void gemm_mlp(
    const float* __restrict__ A,
    const short* __restrict__ BTh, const short* __restrict__ BTl,
    short* __restrict__ Ch, short* __restrict__ Cl,
    const float* __restrict__ bias, int M)
{
    __shared__ short lds_buf[4 * 128 * LROW];
    short* Ah = lds_buf;
    short* Al = lds_buf + 128 * LROW;
    short* Bh = lds_buf + 2 * 128 * LROW;
    short* Bl = lds_buf + 3 * 128 * LROW;

    const int tid = threadIdx.x;
    const int lane = tid & 63, wave = tid >> 6;
    const int wm = wave & 1, wn = wave >> 1;
    const int fr = lane & 15, fg = lane >> 4;
    const int m0 = blockIdx.y * 128;
    const int n0 = blockIdx.x * 128;

    const int sr = tid >> 1;
    const int sc = (tid & 1) * 16;
    const bool avalid = (m0 + sr) < M;
    const int arow = avalid ? (m0 + sr) : (M - 1);

    f32x4 ga[4];
    short8 gbh[2], gbl[2];
    {
        const float* ap = A + (size_t)arow * IN_F + sc;
        const short* bph = BTh + (size_t)(n0 + sr) * IN_F + sc;
        const short* bpl = BTl + (size_t)(n0 + sr) * IN_F + sc;
#pragma unroll
        for (int l = 0; l < 4; ++l) ga[l] = *(const f32x4*)(ap + 4 * l);
        gbh[0] = *(const short8*)bph;  gbh[1] = *(const short8*)(bph + 8);
        gbl[0] = *(const short8*)bpl;  gbl[1] = *(const short8*)(bpl + 8);
    }

    f32x4 acc[4][4];
#pragma unroll
    for (int i = 0; i < 4; ++i)
#pragma unroll
        for (int j = 0; j < 4; ++j) acc[i][j] = (f32x4)0.f;

    const int nk = IN_F / 32;  // 4
    for (int kk = 0; kk < nk; ++kk) {
        __syncthreads();
        {
            short8 vh[2], vl[2];
#pragma unroll
            for (int l = 0; l < 4; ++l) {
                f32x4 v = ga[l];
                if (!avalid) v = (f32x4)0.f;
#pragma unroll
                for (int e = 0; e < 4; ++e) {
                    short hb, lb;
                    f2bf_split(v[e], hb, lb);
                    vh[l >> 1][(l & 1) * 4 + e] = hb;
                    vl[l >> 1][(l & 1) * 4 + e] = lb;
                }
            }
            *(short8*)(Ah + sr * LROW + sc)     = vh[0];
            *(short8*)(Ah + sr * LROW + sc + 8) = vh[1];
            *(short8*)(Al + sr * LROW + sc)     = vl[0];
            *(short8*)(Al + sr * LROW + sc + 8) = vl[1];
            *(short8*)(Bh + sr * LROW + sc)     = gbh[0];
            *(short8*)(Bh + sr * LROW + sc + 8) = gbh[1];
            *(short8*)(Bl + sr * LROW + sc)     = gbl[0];
            *(short8*)(Bl + sr * LROW + sc + 8) = gbl[1];
        }
        __syncthreads();

        if (kk + 1 < nk) {
            int k0 = (kk + 1) * 32;
            const float* ap = A + (size_t)arow * IN_F + k0 + sc;
            const short* bph = BTh + (size_t)(n0 + sr) * IN_F + k0 + sc;
            const short* bpl = BTl + (size_t)(n0 + sr) * IN_F + k0 + sc;
#pragma unroll
            for (int l = 0; l < 4; ++l) ga[l] = *(const f32x4*)(ap + 4 * l);
            gbh[0] = *(const short8*)(bph);  gbh[1] = *(const short8*)(bph + 8);
            gbl[0] = *(const short8*)(bpl);  gbl[1] = *(const short8*)(bpl + 8);
        }

        short8 afh[4], afl[4], bfh[4], bfl[4];
#pragma unroll
        for (int mf = 0; mf < 4; ++mf) {
            int r = wm * 64 + mf * 16 + fr;
            afh[mf] = *(const short8*)(Ah + r * LROW + fg * 8);
            afl[mf] = *(const short8*)(Al + r * LROW + fg * 8);
        }
#pragma unroll
        for (int nf = 0; nf < 4; ++nf) {
            int r = wn * 64 + nf * 16 + fr;
            bfh[nf] = *(const short8*)(Bh + r * LROW + fg * 8);
            bfl[nf] = *(const short8*)(Bl + r * LROW + fg * 8);
        }
#pragma unroll
        for (int mf = 0; mf < 4; ++mf)
#pragma unroll
            for (int nf = 0; nf < 4; ++nf) {
                acc[mf][nf] = __builtin_amdgcn_mfma_f32_16x16x32_bf16(
                    afh[mf], bfh[nf], acc[mf][nf], 0, 0, 0);
                acc[mf][nf] = __builtin_amdgcn_mfma_f32_16x16x32_bf16(
                    afh[mf], bfl[nf], acc[mf][nf], 0, 0, 0);
                acc[mf][nf] = __builtin_amdgcn_mfma_f32_16x16x32_bf16(
                    afl[mf], bfh[nf], acc[mf][nf], 0, 0, 0);
            }
    }

#pragma unroll
    for (int nf = 0; nf < 4; ++nf) {
        int colg = n0 + wn * 64 + nf * 16 + fr;
        float bv = bias[colg];
#pragma unroll
        for (int mf = 0; mf < 4; ++mf) {
            int rowbase = m0 + wm * 64 + mf * 16 + fg * 4;
#pragma unroll
            for (int j = 0; j < 4; ++j) {
                int rowg = rowbase + j;
                if (rowg < M) {
                    float v = fmaxf(acc[mf][nf][j] + bv, 0.f);
                    short hb, lb;
                    f2bf_split(v, hb, lb);
                    size_t idx = (size_t)rowg * H_F + colg;
                    Ch[idx] = hb;
                    Cl[idx] = lb;
                }
            }
        }
    }
}

// ---------------- relation GEMM v5: 256x256 tile, 8 waves, counted-vmcnt dbuf -----
// Round-9 schedule (vmcnt(8) counted, 2 raw barriers, STAGE(kt+2)) at 256x256:
// 8 waves (2M x 4N), per-wave output 128x64, BK=32, LDS 128 KB dbuf.
// 1D grid: wgid -> (mblk, rel) with rel FASTEST + XCD chunk swizzle + hop rotation.
// Swizzle: 16B unit u of row r holds global unit (u-(r>>1))&3; read at
// u=(fg+(r>>1))&3 -> 2-way bank aliasing (free).

__global__ __launch_bounds__(512, 2) void gemm_rel(
    const short* __restrict__ h1h, const short* __restrict__ h1l, long hopStride,
    const short* __restrict__ wch, const short* __restrict__ wcl,
    float* __restrict__ outB, const float* __restrict__ bcB, int M, int nwg)
{
    __shared__ short lds[2][4][8192];  // Ah, Al, Bh, Bl: 256 rows x 32 k each

    // bijective XCD swizzle (m204)
    const int bid = blockIdx.x;
    const int q8 = nwg >> 3, r8 = nwg & 7;
    const int xcd = bid & 7, idx = bid >> 3;
    const int wgid = (xcd < r8) ? (xcd * (q8 + 1) + idx)
                                : (r8 * (q8 + 1) + (xcd - r8) * q8 + idx);
    const int rrel = wgid % R_REL;     // relation fastest -> A m-panel L2-shared
    const int mblk = wgid / R_REL;
    const int m0 = mblk * 256;

    const int tid = threadIdx.x;
    const int lane = tid & 63, wave = tid >> 6;  // 8 waves
    const int wm = wave & 1, wn = wave >> 1;     // 2M x 4N
    const int fr = lane & 15, fg = lane >> 4;

    const short* Agh = h1h + (size_t)rrel * hopStride;
    const short* Agl = h1l + (size_t)rrel * hopStride;
    const short* BTh = wch + (size_t)rrel * 256 * 768;
    const short* BTl = wcl + (size_t)rrel * 256 * 768;
    float* C = outB + (size_t)rrel * H_F;
    const float* bias = bcB + (size_t)rrel * H_F;

    // hop-phase rotation start (in k-steps of 32): r=0..4 -> 0,16,8,0,16
    const int kstart = ((3 - (rrel % 3)) % 3) * 8;

    // staging offsets: call c = wave*2+p covers rows c*16..c*16+15 of a 256-row plane
    int aoff[2], boff[2], loff[2];
#pragma unroll
    for (int p = 0; p < 2; ++p) {
        int c = wave * 2 + p;
        int r = c * 16 + (lane >> 2);
        int u = lane & 3;
        int g = (u - (r >> 1)) & 3;
        int ar = m0 + r; if (ar >= M) ar = M - 1;
        aoff[p] = ar * H_F + g * 8;        // A row stride 256 shorts
        boff[p] = r * 768 + g * 8;         // B row stride 768 shorts (n0 = 0)
        loff[p] = c * 512;                 // 1KB per wave-call
    }

#define STAGE_REL(buf, kg) do {                                                  \
        int hop_ = (kg) >> 8, kin_ = (kg) & 255;                                 \
        const short* ah_ = Agh + (size_t)hop_ * hopStride + kin_;                \
        const short* al_ = Agl + (size_t)hop_ * hopStride + kin_;                \
        const short* bh_ = BTh + (kg);                                           \
        const short* bl_ = BTl + (kg);                                           \
        GLOAD16(ah_ + aoff[0], &lds[buf][0][loff[0]]);                           \
        GLOAD16(ah_ + aoff[1], &lds[buf][0][loff[1]]);                           \
        GLOAD16(al_ + aoff[0], &lds[buf][1][loff[0]]);                           \
        GLOAD16(al_ + aoff[1], &lds[buf][1][loff[1]]);                           \
        GLOAD16(bh_ + boff[0], &lds[buf][2][loff[0]]);                           \
        GLOAD16(bh_ + boff[1], &lds[buf][2][loff[1]]);                           \
        GLOAD16(bl_ + boff[0], &lds[buf][3][loff[0]]);                           \
        GLOAD16(bl_ + boff[1], &lds[buf][3][loff[1]]);                           \
    } while (0)

#define KIDX(t) ((((t) + kstart) % nk) * 32)

    f32x4 acc[8][4];
#pragma unroll
    for (int i = 0; i < 8; ++i)
#pragma unroll
        for (int j = 0; j < 4; ++j) acc[i][j] = (f32x4)0.f;

    const int nk = 768 / 32;  // 24

    // prologue: fill both buffers; 16 loads in flight per wave
    STAGE_REL(0, KIDX(0));
    STAGE_REL(1, KIDX(1));

    int cur = 0;
    for (int kt = 0; kt < nk; ++kt) {
        // wait for buf[cur]'s 8 loads; leave the next tile's 8 in flight (T4)
        if (kt + 1 < nk) {
            asm volatile("s_waitcnt vmcnt(8)" ::: "memory");
        } else {
            asm volatile("s_waitcnt vmcnt(0)" ::: "memory");
        }
        __builtin_amdgcn_sched_barrier(0);
        __builtin_amdgcn_s_barrier();          // all waves' buf[cur] data published
        __builtin_amdgcn_sched_barrier(0);

        const short* Ahc = &lds[cur][0][0];
        const short* Alc = &lds[cur][1][0];
        const short* Bhc = &lds[cur][2][0];
        const short* Blc = &lds[cur][3][0];

        short8 bfh[4], bfl[4];
#pragma unroll
        for (int nf = 0; nf < 4; ++nf) {
            int rb = wn * 64 + nf * 16 + fr;
            int ub = (fg + (rb >> 1)) & 3;
            bfh[nf] = *(const short8*)(Bhc + rb * 32 + ub * 8);
            bfl[nf] = *(const short8*)(Blc + rb * 32 + ub * 8);
        }
        __builtin_amdgcn_s_setprio(1);
#pragma unroll
        for (int mf = 0; mf < 8; ++mf) {
            int ra = wm * 128 + mf * 16 + fr;
            int ua = (fg + (ra >> 1)) & 3;
            short8 ah = *(const short8*)(Ahc + ra * 32 + ua * 8);
            short8 al = *(const short8*)(Alc + ra * 32 + ua * 8);
#pragma unroll
            for (int nf = 0; nf < 4; ++nf) {
                acc[mf][nf] = __builtin_amdgcn_mfma_f32_16x16x32_bf16(
                    ah, bfh[nf], acc[mf][nf], 0, 0, 0);
                acc[mf][nf] = __builtin_amdgcn_mfma_f32_16x16x32_bf16(
                    ah, bfl[nf], acc[mf][nf], 0, 0, 0);
                acc[mf][nf] = __builtin_amdgcn_mfma_f32_16x16x32_bf16(
                    al, bfh[nf], acc[mf][nf], 0, 0, 0);
            }
        }
        __builtin_amdgcn_s_setprio(0);

        __builtin_amdgcn_sched_barrier(0);
        __builtin_amdgcn_s_barrier();          // all waves' reads of buf[cur] done
        __builtin_amdgcn_sched_barrier(0);

        if (kt + 2 < nk) STAGE_REL(cur, KIDX(kt + 2));  // overwrite now safe
        cur ^= 1;
    }

#pragma unroll
    for (int nf = 0; nf < 4; ++nf) {
        int colg = wn * 64 + nf * 16 + fr;     // n0 = 0
        float bv = bias[colg];
#pragma unroll
        for (int mf = 0; mf < 8; ++mf) {
            int rowbase = m0 + wm * 128 + mf * 16 + fg * 4;
#pragma unroll
            for (int j = 0; j < 4; ++j) {
                int rowg = rowbase + j;
                if (rowg < M)
                    C[(size_t)rowg * OUT_W + colg] = fmaxf(acc[mf][nf][j] + bv, 0.f);
            }
        }
    }
#undef STAGE_REL
#undef KIDX
}

// ---------------- fallback relation GEMM (pre-split A, reg-staged) ----------------
// MODE: 0 = bias, 2 = accum, 3 = accum+relu   (non-windowed path only)

template <int MODE>
__global__ __launch_bounds__(256, 2) void gemm_presplit(
    const short* __restrict__ Agh, const short* __restrict__ Agl, int lda,
    const short* __restrict__ BTh, const short* __restrict__ BTl, int ldb, int Kd,
    float* __restrict__ C, int ldc, const float* __restrict__ bias, int M)
{
    __shared__ short lds_buf[4 * 128 * LROW];
    short* Ah = lds_buf;
    short* Al = lds_buf + 128 * LROW;
    short* Bh = lds_buf + 2 * 128 * LROW;
    short* Bl = lds_buf + 3 * 128 * LROW;

    const int tid = threadIdx.x;
    const int lane = tid & 63, wave = tid >> 6;
    const int wm = wave & 1, wn = wave >> 1;
    const int fr = lane & 15, fg = lane >> 4;
    const int m0 = blockIdx.y * 128;
    const int n0 = blockIdx.x * 128;

    const int sr = tid >> 1;
    const int sc = (tid & 1) * 16;
    const bool avalid = (m0 + sr) < M;
    const int arow = avalid ? (m0 + sr) : (M - 1);

    short8 gah[2], gal[2], gbh[2], gbl[2];
    {
        const short* aph = Agh + (size_t)arow * lda + sc;
        const short* apl = Agl + (size_t)arow * lda + sc;
        const short* bph = BTh + (size_t)(n0 + sr) * ldb + sc;
        const short* bpl = BTl + (size_t)(n0 + sr) * ldb + sc;
        gah[0] = *(const short8*)aph;  gah[1] = *(const short8*)(aph + 8);
        gal[0] = *(const short8*)apl;  gal[1] = *(const short8*)(apl + 8);
        gbh[0] = *(const short8*)bph;  gbh[1] = *(const short8*)(bph + 8);
        gbl[0] = *(const short8*)bpl;  gbl[1] = *(const short8*)(bpl + 8);
    }

    f32x4 acc[4][4];
#pragma unroll
    for (int i = 0; i < 4; ++i)
#pragma unroll
        for (int j = 0; j < 4; ++j) acc[i][j] = (f32x4)0.f;

    const int nk = Kd / 32;
    for (int kk = 0; kk < nk; ++kk) {
        __syncthreads();
        *(short8*)(Ah + sr * LROW + sc)     = gah[0];
        *(short8*)(Ah + sr * LROW + sc + 8) = gah[1];
        *(short8*)(Al + sr * LROW + sc)     = gal[0];
        *(short8*)(Al + sr * LROW + sc + 8) = gal[1];
        *(short8*)(Bh + sr * LROW + sc)     = gbh[0];
        *(short8*)(Bh + sr * LROW + sc + 8) = gbh[1];
        *(short8*)(Bl + sr * LROW + sc)     = gbl[0];
        *(short8*)(Bl + sr * LROW + sc + 8) = gbl[1];
        __syncthreads();

        if (kk + 1 < nk) {
            int k0 = (kk + 1) * 32;
            const short* aph = Agh + (size_t)arow * lda + k0 + sc;
            const short* apl = Agl + (size_t)arow * lda + k0 + sc;
            const short* bph = BTh + (size_t)(n0 + sr) * ldb + k0 + sc;
            const short* bpl = BTl + (size_t)(n0 + sr) * ldb + k0 + sc;
            gah[0] = *(const short8*)aph;  gah[1] = *(const short8*)(aph + 8);
            gal[0] = *(const short8*)apl;  gal[1] = *(const short8*)(apl + 8);
            gbh[0] = *(const short8*)bph;  gbh[1] = *(const short8*)(bph + 8);
            gbl[0] = *(const short8*)bpl;  gbl[1] = *(const short8*)(bpl + 8);
        }

        short8 afh[4], afl[4], bfh[4], bfl[4];
#pragma unroll
        for (int mf = 0; mf < 4; ++mf) {
            int r = wm * 64 + mf * 16 + fr;
            afh[mf] = *(const short8*)(Ah + r * LROW + fg * 8);
            afl[mf] = *(const short8*)(Al + r * LROW + fg * 8);
        }
#pragma unroll
        for (int nf = 0; nf < 4; ++nf) {
            int r = wn * 64 + nf * 16 + fr;
            bfh[nf] = *(const short8*)(Bh + r * LROW + fg * 8);
            bfl[nf] = *(const short8*)(Bl + r * LROW + fg * 8);
        }
#pragma unroll
        for (int mf = 0; mf < 4; ++mf)
#pragma unroll
            for (int nf = 0; nf < 4; ++nf) {
                acc[mf][nf] = __builtin_amdgcn_mfma_f32_16x16x32_bf16(
                    afh[mf], bfh[nf], acc[mf][nf], 0, 0, 0);
                acc[mf][nf] = __builtin_amdgcn_mfma_f32_16x16x32_bf16(
                    afh[mf], bfl[nf], acc[mf][nf], 0, 0, 0);
                acc[mf][nf] = __builtin_amdgcn_mfma_f32_16x16x32_bf16(
                    afl[mf], bfh[nf], acc[mf][nf], 0, 0, 0);
            }
    }

#pragma unroll
    for (int nf = 0; nf < 4; ++nf) {
        int colg = n0 + wn * 64 + nf * 16 + fr;
        float bv = (MODE == 0) ? bias[colg] : 0.f;
#pragma unroll
        for (int mf = 0; mf < 4; ++mf) {
            int rowbase = m0 + wm * 64 + mf * 16 + fg * 4;
#pragma unroll
            for (int j = 0; j < 4; ++j) {
                int rowg = rowbase + j;
                if (rowg < M) {
                    size_t idx = (size_t)rowg * ldc + colg;
                    float v = acc[mf][nf][j] + bv;
                    if (MODE >= 2) v += C[idx];
                    if (MODE & 1) v = fmaxf(v, 0.f);
                    C[idx] = v;
                }
            }
        }
    }
}

// ---------------- driver ----------------

extern "C" void kernel_launch(void* const* d_in, const int* in_sizes, int n_in,
                              void* d_out, int out_size, void* d_ws, size_t ws_size,
                              hipStream_t stream) {
    const float* features = (const float*)d_in[0];
    const float* W1 = (const float*)d_in[1];
    const float* b1 = (const float*)d_in[2];
    const float* W2 = (const float*)d_in[3];
    const float* b2 = (const float*)d_in[4];
    const float* Wr = (const float*)d_in[5];
    const float* br = (const float*)d_in[6];
    const int* row = (const int*)d_in[7];
    const int* col = (const int*)d_in[8];
    float* out = (float*)d_out;

    // workspace layout (byte offsets; ws_size ~1953 MiB)
    char* ws = (char*)d_ws;
    int* deg = (int*)ws;                                 // 400KB (also cursor)
    int* rowptr = (int*)(ws + (1ull << 20));
    float* dinv = (float*)(ws + (2ull << 20));
    int* bsum = (int*)(ws + (3ull << 20));               // SCAN_B+1 ints
    int* cols2 = (int*)(ws + (4ull << 20));              // 6.4MB
    float* ew = (float*)(ws + (11ull << 20));            // 6.4MB
    short* w1h = (short*)(ws + (18ull << 20));           // 459KB
    short* w1l = (short*)(ws + (19ull << 20));
    float* wc32 = (float*)(ws + (20ull << 20));          // 3.93MB
    short* wch = (short*)(ws + (24ull << 20));           // 1.97MB
    short* wcl = (short*)(ws + (26ull << 20));
    float* bc = (float*)(ws + (28ull << 20));            // 5KB
    float* xa = (float*)(ws + (32ull << 20));            // 51.2MB
    float* xb = (float*)(ws + (96ull << 20));            // 51.2MB
    short* h1h = (short*)(ws + (160ull << 20));          // 341.8MiB (windowed)
    short* h1l = (short*)(ws + (576ull << 20));          // 341.8MiB

    const bool windowed = ws_size >= (1000ull << 20);

    // ---- adjacency normalization + CSR build ----
    zero_int<<<(N_NODES + 255) / 256, 256, 0, stream>>>(deg, N_NODES);
    deg_count<<<(E_EDGES + 255) / 256, 256, 0, stream>>>(row, deg);
    dinv_compute<<<(N_NODES + 255) / 256, 256, 0, stream>>>(deg, dinv);
    scan1<<<SCAN_B, 1024, 0, stream>>>(deg, rowptr, bsum);
    scan2<<<1, 128, 0, stream>>>(bsum);
    scan3<<<SCAN_B, 1024, 0, stream>>>(rowptr, bsum);
    zero_int<<<(N_NODES + 255) / 256, 256, 0, stream>>>(deg, N_NODES);
    csr_scatter<<<(E_EDGES + 255) / 256, 256, 0, stream>>>(row, col, dinv, rowptr,
                                                           deg, cols2, ew);

    // ---- weight fusion: Wc = W2 @ WrS, bc = br + b2 @ WrS ----
    wc_compute<<<dim3(15, 32), 256, 0, stream>>>(W2, Wr, wc32);
    bc_compute<<<R_REL, 256, 0, stream>>>(b2, Wr, br, bc);

    // ---- weight transpose + bf16 split ----
    dim3 tb(32, 8);
    transpose_convert<<<dim3(IN_F / 32, 8, K_HOPS), tb, 0, stream>>>(W1, w1h, w1l, IN_F, 1);
    transpose_convert<<<dim3(H_F / 32, 8, 15), tb, 0, stream>>>(wc32, wch, wcl, H_F, 3);

    // ---- hop loop: MLP1 (fp32 A in, split bf16 out); then propagate ----
    const float* xcur = features;
    float* bufs[2] = {xa, xb};
    for (int k = 0; k < K_HOPS; ++k) {
        short* h1hd = windowed ? (h1h + (size_t)k * N_NODES * H_F) : h1h;
        short* h1ld = windowed ? (h1l + (size_t)k * N_NODES * H_F) : h1l;
        dim3 grid(2, (N_NODES + 127) / 128);
        gemm_mlp<<<grid, 256, 0, stream>>>(xcur, w1h + (size_t)k * 256 * IN_F,
                                           w1l + (size_t)k * 256 * IN_F,
                                           h1hd, h1ld, b1 + (size_t)k * H_F, N_NODES);

        if (!windowed) {
            int rlo = (k - 2 < 0) ? 0 : (k - 2);
            int rhi = (k < R_REL - 1) ? k : (R_REL - 1);
            for (int r = rlo; r <= rhi; ++r) {
                int d = k - r;
                const short* Bh = wch + (size_t)r * 256 * 768 + (size_t)d * H_F;
                const short* Bl = wcl + (size_t)r * 256 * 768 + (size_t)d * H_F;
                float* Cp = out + (size_t)r * H_F;
                if (k == r)
                    gemm_presplit<0><<<grid, 256, 0, stream>>>(
                        h1h, h1l, H_F, Bh, Bl, 768, H_F, Cp, OUT_W,
                        bc + (size_t)r * H_F, N_NODES);
                else if (k == r + 2)
                    gemm_presplit<3><<<grid, 256, 0, stream>>>(
                        h1h, h1l, H_F, Bh, Bl, 768, H_F, Cp, OUT_W, nullptr, N_NODES);
                else
                    gemm_presplit<2><<<grid, 256, 0, stream>>>(
                        h1h, h1l, H_F, Bh, Bl, 768, H_F, Cp, OUT_W, nullptr, N_NODES);
            }
        }

        if (k < K_HOPS - 1) {
            float* xn = bufs[k & 1];
            spmm_csr<<<(N_NODES + 3) / 4, 256, 0, stream>>>(
                (const float4*)xcur, rowptr, cols2, ew, dinv, (float4*)xn);
            xcur = xn;
        }
    }

    if (windowed) {
        // all 5 relation GEMMs in one 1D launch; 256x256 tiles, rel-fastest decode
        int mblocks = (N_NODES + 255) / 256;
        int nwg = mblocks * R_REL;
        gemm_rel<<<nwg, 512, 0, stream>>>(h1h, h1l, (long)N_NODES * H_F,
                                          wch, wcl, out, bc, N_NODES, nwg);
    }
}

// Round 16
// 2148.369 us; speedup vs baseline: 2.1362x; 1.0124x over previous
//
#include <hip/hip_runtime.h>

#define N_NODES 100000
#define E_EDGES 1600000
#define IN_F 128
#define H_F 256
#define K_HOPS 7
#define R_REL 5
#define OUT_W (R_REL * H_F)  // 1280
#define SCAN_B ((N_NODES + 1023) / 1024)  // 98

typedef __attribute__((ext_vector_type(8))) short short8;
typedef __attribute__((ext_vector_type(4))) float f32x4;

// async global->LDS, 16B per lane; lds dest = base + lane*16
#define GLOAD16(g, l) __builtin_amdgcn_global_load_lds( \
    (const __attribute__((address_space(1))) void*)(g), \
    (__attribute__((address_space(3))) void*)(l), 16, 0, 0)

// ---------------- small utility kernels ----------------

__global__ void zero_int(int* __restrict__ p, int n) {
    int t = blockIdx.x * blockDim.x + threadIdx.x;
    if (t < n) p[t] = 0;
}

__global__ void deg_count(const int* __restrict__ row, int* __restrict__ deg) {
    int e = blockIdx.x * blockDim.x + threadIdx.x;
    if (e < E_EDGES) atomicAdd(&deg[row[e]], 1);
}

__global__ void dinv_compute(const int* __restrict__ deg, float* __restrict__ dinv) {
    int i = blockIdx.x * blockDim.x + threadIdx.x;
    if (i < N_NODES) dinv[i] = rsqrtf((float)(deg[i] + 1));
}

// ---- 3-pass exclusive scan of deg -> rowptr ----
__global__ __launch_bounds__(1024) void scan1(const int* __restrict__ deg,
                                              int* __restrict__ rp, int* __restrict__ bsum) {
    __shared__ int ws[16];
    const int t = threadIdx.x, lane = t & 63, wv = t >> 6;
    int i = blockIdx.x * 1024 + t;
    int v = (i < N_NODES) ? deg[i] : 0;
    int x = v;
#pragma unroll
    for (int off = 1; off < 64; off <<= 1) {
        int n = __shfl_up(x, off, 64);
        if (lane >= off) x += n;
    }
    if (lane == 63) ws[wv] = x;
    __syncthreads();
    if (wv == 0 && lane < 16) {
        int s = ws[lane];
#pragma unroll
        for (int off = 1; off < 16; off <<= 1) {
            int n = __shfl_up(s, off, 64);
            if (lane >= off) s += n;
        }
        ws[lane] = s;
    }
    __syncthreads();
    int wbase = (wv == 0) ? 0 : ws[wv - 1];
    if (i < N_NODES) rp[i] = wbase + x - v;
    if (t == 1023) bsum[blockIdx.x] = ws[15];
}

// parallel scan of the 98 block sums (one block, 128 threads = 2 waves)
__global__ __launch_bounds__(128) void scan2(int* __restrict__ bsum) {
    __shared__ int wtot[2];
    const int t = threadIdx.x, lane = t & 63, wv = t >> 6;
    int v = (t < SCAN_B) ? bsum[t] : 0;
    int x = v;
#pragma unroll
    for (int off = 1; off < 64; off <<= 1) {
        int n = __shfl_up(x, off, 64);
        if (lane >= off) x += n;
    }
    if (lane == 63) wtot[wv] = x;
    __syncthreads();
    int base = (wv == 1) ? wtot[0] : 0;
    if (t < SCAN_B) bsum[t] = base + x - v;
    if (t == 127) bsum[SCAN_B] = wtot[0] + wtot[1];
}

__global__ __launch_bounds__(1024) void scan3(int* __restrict__ rp,
                                              const int* __restrict__ bsum) {
    int i = blockIdx.x * 1024 + threadIdx.x;
    if (i < N_NODES) rp[i] += bsum[blockIdx.x];
    if (i == 0) rp[N_NODES] = bsum[SCAN_B];
}

__global__ void csr_scatter(const int* __restrict__ row, const int* __restrict__ col,
                            const float* __restrict__ dinv, const int* __restrict__ rowptr,
                            int* __restrict__ cursor, int* __restrict__ cols2,
                            float* __restrict__ ew) {
    int e = blockIdx.x * blockDim.x + threadIdx.x;
    if (e >= E_EDGES) return;
    int r = row[e], c = col[e];
    int pos = rowptr[r] + atomicAdd(&cursor[r], 1);
    cols2[pos] = c;
    ew[pos] = dinv[r] * dinv[c];
}

// y[i] = dinv[i]^2 * x[i] + sum_j w[j] * x[cols[j]]
// one wave per row; 2 edge slots x 32 lanes x float4; 4-deep unroll per slot
__global__ __launch_bounds__(256) void spmm_csr(
    const float4* __restrict__ x, const int* __restrict__ rowptr,
    const int* __restrict__ cols, const float* __restrict__ w,
    const float* __restrict__ dinv, float4* __restrict__ y) {
    const int wave = threadIdx.x >> 6, lane = threadIdx.x & 63;
    const int i = blockIdx.x * 4 + wave;
    if (i >= N_NODES) return;
    const int fh = lane & 31;
    const int slot = lane >> 5;
    const int jb = rowptr[i];
    const int cnt = rowptr[i + 1] - jb;

    float4 acc = make_float4(0.f, 0.f, 0.f, 0.f);
    int t = slot;
    for (; t + 6 < cnt; t += 8) {
        int c0 = cols[jb + t],     c1 = cols[jb + t + 2];
        int c2 = cols[jb + t + 4], c3 = cols[jb + t + 6];
        float ww0 = w[jb + t],     ww1 = w[jb + t + 2];
        float ww2 = w[jb + t + 4], ww3 = w[jb + t + 6];
        float4 v0 = x[(size_t)c0 * 32 + fh];
        float4 v1 = x[(size_t)c1 * 32 + fh];
        float4 v2 = x[(size_t)c2 * 32 + fh];
        float4 v3 = x[(size_t)c3 * 32 + fh];
        acc.x += ww0 * v0.x + ww1 * v1.x + ww2 * v2.x + ww3 * v3.x;
        acc.y += ww0 * v0.y + ww1 * v1.y + ww2 * v2.y + ww3 * v3.y;
        acc.z += ww0 * v0.z + ww1 * v1.z + ww2 * v2.z + ww3 * v3.z;
        acc.w += ww0 * v0.w + ww1 * v1.w + ww2 * v2.w + ww3 * v3.w;
    }
    for (; t < cnt; t += 2) {
        int c0 = cols[jb + t];
        float ww0 = w[jb + t];
        float4 v0 = x[(size_t)c0 * 32 + fh];
        acc.x += ww0 * v0.x;
        acc.y += ww0 * v0.y;
        acc.z += ww0 * v0.z;
        acc.w += ww0 * v0.w;
    }
    acc.x += __shfl_xor(acc.x, 32);
    acc.y += __shfl_xor(acc.y, 32);
    acc.z += __shfl_xor(acc.z, 32);
    acc.w += __shfl_xor(acc.w, 32);
    if (slot == 0) {
        float d = dinv[i];
        float s = d * d;
        float4 xv = x[(size_t)i * 32 + fh];
        acc.x += s * xv.x;
        acc.y += s * xv.y;
        acc.z += s * xv.z;
        acc.w += s * xv.w;
        y[(size_t)i * 32 + fh] = acc;
    }
}

// ---------------- bf16 split helpers ----------------

__device__ __forceinline__ void f2bf_split(float v, short& h, short& l) {
    unsigned u = __float_as_uint(v);
    unsigned hb = (u + 0x7FFFu + ((u >> 16) & 1u)) >> 16;  // RN-to-even bf16
    float fh = __uint_as_float(hb << 16);
    float r = v - fh;
    unsigned u2 = __float_as_uint(r);
    unsigned lb = (u2 + 0x7FFFu + ((u2 >> 16) & 1u)) >> 16;
    h = (short)(unsigned short)hb;
    l = (short)(unsigned short)lb;
}

// ---------------- weight-fusion precompute ----------------
// Wc[z=r*3+d] = W2[r+d] @ WrS[r,d]; 8 j-rows per block via LDS A tile
__global__ __launch_bounds__(256) void wc_compute(const float* __restrict__ W2,
                                                  const float* __restrict__ Wr,
                                                  float* __restrict__ Wc) {
    __shared__ float as[8][256];
    const int z = blockIdx.x, j0 = blockIdx.y * 8, g = threadIdx.x;
    const int r = z / 3, d = z % 3, hop = r + d;
    const float* a = W2 + (size_t)hop * H_F * H_F + (size_t)j0 * H_F;
    for (int t = threadIdx.x; t < 8 * 256; t += 256)
        as[t >> 8][t & 255] = a[t];
    __syncthreads();
    const float* b = Wr + ((size_t)r * 768 + (size_t)d * H_F) * H_F + g;
    float acc[8] = {0.f, 0.f, 0.f, 0.f, 0.f, 0.f, 0.f, 0.f};
    for (int h = 0; h < H_F; ++h) {
        float bv = b[(size_t)h * H_F];
#pragma unroll
        for (int jj = 0; jj < 8; ++jj) acc[jj] += as[jj][h] * bv;
    }
#pragma unroll
    for (int jj = 0; jj < 8; ++jj)
        Wc[(size_t)z * H_F * H_F + (size_t)(j0 + jj) * H_F + g] = acc[jj];
}

// bc[r] = br[r] + sum_{d,h} b2[r+d][h] * WrS[r,d][h][:]
__global__ __launch_bounds__(256) void bc_compute(const float* __restrict__ b2,
                                                  const float* __restrict__ Wr,
                                                  const float* __restrict__ br,
                                                  float* __restrict__ bc) {
    const int r = blockIdx.x, g = threadIdx.x;
    float acc = br[(size_t)r * H_F + g];
    for (int t = 0; t < 3 * H_F; ++t) {
        float bv = b2[(size_t)(r + t / H_F) * H_F + (t % H_F)];
        acc += bv * Wr[((size_t)r * 768 + t) * H_F + g];
    }
    bc[(size_t)r * H_F + g] = acc;
}

// weight transpose+split: in [z][Kd][256] fp32 -> out group (z/grp) is [256][grp*Kd]
__global__ void transpose_convert(const float* __restrict__ in, short* __restrict__ oh,
                                  short* __restrict__ ol, int Kd, int grp) {
    __shared__ float t[32][33];
    const int i0 = blockIdx.x * 32, n0 = blockIdx.y * 32, z = blockIdx.z;
    const int tx = threadIdx.x, ty = threadIdx.y;
    const int outLd = grp * Kd;
    const float* ip = in + (size_t)z * Kd * 256;
#pragma unroll
    for (int j = 0; j < 4; ++j)
        t[ty + 8 * j][tx] = ip[(size_t)(i0 + ty + 8 * j) * 256 + n0 + tx];
    __syncthreads();
    size_t base = (size_t)(z / grp) * 256 * outLd + (size_t)(z % grp) * Kd;
#pragma unroll
    for (int j = 0; j < 4; ++j) {
        float v = t[tx][ty + 8 * j];
        short hb, lb;
        f2bf_split(v, hb, lb);
        size_t o = base + (size_t)(n0 + ty + 8 * j) * outLd + i0 + tx;
        oh[o] = hb;
        ol[o] = lb;
    }
}

// ---------------- MLP1 GEMM: fp32 A, in-kernel split, split-bf16 output ----------------
// Ch/Cl[M,256] = relu(A[M,128] @ B[128,256] + bias), reg-staged, LROW=40 pad

#define LROW 40

__global__ __launch_bounds__(256, 2) void gemm_mlp(
    const float* __restrict__ A,
    const short* __restrict__ BTh, const short* __restrict__ BTl,
    short* __restrict__ Ch, short* __restrict__ Cl,
    const float* __restrict__ bias, int M)
{
    __shared__ short lds_buf[4 * 128 * LROW];
    short* Ah = lds_buf;
    short* Al = lds_buf + 128 * LROW;
    short* Bh = lds_buf + 2 * 128 * LROW;
    short* Bl = lds_buf + 3 * 128 * LROW;

    const int tid = threadIdx.x;
    const int lane = tid & 63, wave = tid >> 6;
    const int wm = wave & 1, wn = wave >> 1;
    const int fr = lane & 15, fg = lane >> 4;
    const int m0 = blockIdx.y * 128;
    const int n0 = blockIdx.x * 128;

    const int sr = tid >> 1;
    const int sc = (tid & 1) * 16;
    const bool avalid = (m0 + sr) < M;
    const int arow = avalid ? (m0 + sr) : (M - 1);

    f32x4 ga[4];
    short8 gbh[2], gbl[2];
    {
        const float* ap = A + (size_t)arow * IN_F + sc;
        const short* bph = BTh + (size_t)(n0 + sr) * IN_F + sc;
        const short* bpl = BTl + (size_t)(n0 + sr) * IN_F + sc;
#pragma unroll
        for (int l = 0; l < 4; ++l) ga[l] = *(const f32x4*)(ap + 4 * l);
        gbh[0] = *(const short8*)bph;  gbh[1] = *(const short8*)(bph + 8);
        gbl[0] = *(const short8*)bpl;  gbl[1] = *(const short8*)(bpl + 8);
    }

    f32x4 acc[4][4];
#pragma unroll
    for (int i = 0; i < 4; ++i)
#pragma unroll
        for (int j = 0; j < 4; ++j) acc[i][j] = (f32x4)0.f;

    const int nk = IN_F / 32;  // 4
    for (int kk = 0; kk < nk; ++kk) {
        __syncthreads();
        {
            short8 vh[2], vl[2];
#pragma unroll
            for (int l = 0; l < 4; ++l) {
                f32x4 v = ga[l];
                if (!avalid) v = (f32x4)0.f;
#pragma unroll
                for (int e = 0; e < 4; ++e) {
                    short hb, lb;
                    f2bf_split(v[e], hb, lb);
                    vh[l >> 1][(l & 1) * 4 + e] = hb;
                    vl[l >> 1][(l & 1) * 4 + e] = lb;
                }
            }
            *(short8*)(Ah + sr * LROW + sc)     = vh[0];
            *(short8*)(Ah + sr * LROW + sc + 8) = vh[1];
            *(short8*)(Al + sr * LROW + sc)     = vl[0];
            *(short8*)(Al + sr * LROW + sc + 8) = vl[1];
            *(short8*)(Bh + sr * LROW + sc)     = gbh[0];
            *(short8*)(Bh + sr * LROW + sc + 8) = gbh[1];
            *(short8*)(Bl + sr * LROW + sc)     = gbl[0];
            *(short8*)(Bl + sr * LROW + sc + 8) = gbl[1];
        }
        __syncthreads();

        if (kk + 1 < nk) {
            int k0 = (kk + 1) * 32;
            const float* ap = A + (size_t)arow * IN_F + k0 + sc;
            const short* bph = BTh + (size_t)(n0 + sr) * IN_F + k0 + sc;
            const short* bpl = BTl + (size_t)(n0 + sr) * IN_F + k0 + sc;
#pragma unroll
            for (int l = 0; l < 4; ++l) ga[l] = *(const f32x4*)(ap + 4 * l);
            gbh[0] = *(const short8*)(bph);  gbh[1] = *(const short8*)(bph + 8);
            gbl[0] = *(const short8*)(bpl);  gbl[1] = *(const short8*)(bpl + 8);
        }

        short8 afh[4], afl[4], bfh[4], bfl[4];
#pragma unroll
        for (int mf = 0; mf < 4; ++mf) {
            int r = wm * 64 + mf * 16 + fr;
            afh[mf] = *(const short8*)(Ah + r * LROW + fg * 8);
            afl[mf] = *(const short8*)(Al + r * LROW + fg * 8);
        }
#pragma unroll
        for (int nf = 0; nf < 4; ++nf) {
            int r = wn * 64 + nf * 16 + fr;
            bfh[nf] = *(const short8*)(Bh + r * LROW + fg * 8);
            bfl[nf] = *(const short8*)(Bl + r * LROW + fg * 8);
        }
#pragma unroll
        for (int mf = 0; mf < 4; ++mf)
#pragma unroll
            for (int nf = 0; nf < 4; ++nf) {
                acc[mf][nf] = __builtin_amdgcn_mfma_f32_16x16x32_bf16(
                    afh[mf], bfh[nf], acc[mf][nf], 0, 0, 0);
                acc[mf][nf] = __builtin_amdgcn_mfma_f32_16x16x32_bf16(
                    afh[mf], bfl[nf], acc[mf][nf], 0, 0, 0);
                acc[mf][nf] = __builtin_amdgcn_mfma_f32_16x16x32_bf16(
                    afl[mf], bfh[nf], acc[mf][nf], 0, 0, 0);
            }
    }

#pragma unroll
    for (int nf = 0; nf < 4; ++nf) {
        int colg = n0 + wn * 64 + nf * 16 + fr;
        float bv = bias[colg];
#pragma unroll
        for (int mf = 0; mf < 4; ++mf) {
            int rowbase = m0 + wm * 64 + mf * 16 + fg * 4;
#pragma unroll
            for (int j = 0; j < 4; ++j) {
                int rowg = rowbase + j;
                if (rowg < M) {
                    float v = fmaxf(acc[mf][nf][j] + bv, 0.f);
                    short hb, lb;
                    f2bf_split(v, hb, lb);
                    size_t idx = (size_t)rowg * H_F + colg;
                    Ch[idx] = hb;
                    Cl[idx] = lb;
                }
            }
        }
    }
}

// ---------------- relation GEMM v6: 256x256, 4-phase/K-step interleave (T3+T4) ----
// Phase p computes mf in {p, p+4} (24 MFMAs); phase p's end-barrier releases
// exactly A-chunks c = p mod 4 (16 rows each) and phase 0 releases all B rows.
// STAGE(kt+2) gloads are issued at the start of the phase AFTER their target
// region's release: B + even-wave A-call0 @ phase 1; even-wave A-call1 @ phase 2;
// odd-wave A-call0 @ phase 3; odd-wave A-call1 after phase 3. Per-wave issue
// stays 8 loads/K-step -> entry vmcnt(8) accounting identical to v5.
// Swizzle: 16B unit u of row r holds global unit (u-(r>>1))&3; read at
// u=(fg+(r>>1))&3 -> 2-way bank aliasing (free).

__device__ __forceinline__ f32x4 mfma16(short8 a, short8 b, f32x4 c) {
    return __builtin_amdgcn_mfma_f32_16x16x32_bf16(a, b, c, 0, 0, 0);
}

template <int MFA, int MFB>
__device__ __forceinline__ void rel_phase(
    const short* Ahc, const short* Alc,
    const short8* bfh, const short8* bfl,
    f32x4 (&acc)[8][4], int wm, int fr, int fg)
{
    const int ra0 = wm * 128 + MFA * 16 + fr;
    const int ua0 = (fg + (ra0 >> 1)) & 3;
    short8 ahA = *(const short8*)(Ahc + ra0 * 32 + ua0 * 8);
    short8 alA = *(const short8*)(Alc + ra0 * 32 + ua0 * 8);
    const int ra1 = wm * 128 + MFB * 16 + fr;
    const int ua1 = (fg + (ra1 >> 1)) & 3;
    short8 ahB = *(const short8*)(Ahc + ra1 * 32 + ua1 * 8);
    short8 alB = *(const short8*)(Alc + ra1 * 32 + ua1 * 8);
    __builtin_amdgcn_sched_barrier(0);
    __builtin_amdgcn_s_barrier();
    asm volatile("s_waitcnt lgkmcnt(0)" ::: "memory");
    __builtin_amdgcn_sched_barrier(0);
    __builtin_amdgcn_s_setprio(1);
#pragma unroll
    for (int nf = 0; nf < 4; ++nf) {
        acc[MFA][nf] = mfma16(ahA, bfh[nf], acc[MFA][nf]);
        acc[MFA][nf] = mfma16(ahA, bfl[nf], acc[MFA][nf]);
        acc[MFA][nf] = mfma16(alA, bfh[nf], acc[MFA][nf]);
        acc[MFB][nf] = mfma16(ahB, bfh[nf], acc[MFB][nf]);
        acc[MFB][nf] = mfma16(ahB, bfl[nf], acc[MFB][nf]);
        acc[MFB][nf] = mfma16(alB, bfh[nf], acc[MFB][nf]);
    }
    __builtin_amdgcn_s_setprio(0);
    __builtin_amdgcn_sched_barrier(0);
    __builtin_amdgcn_s_barrier();
    __builtin_amdgcn_sched_barrier(0);
}

__global__ __launch_bounds__(512, 2) void gemm_rel(
    const short* __restrict__ h1h, const short* __restrict__ h1l, long hopStride,
    const short* __restrict__ wch, const short* __restrict__ wcl,
    float* __restrict__ outB, const float* __restrict__ bcB, int M, int nwg)
{
    __shared__ short lds[2][4][8192];  // Ah, Al, Bh, Bl: 256 rows x 32 k each

    // bijective XCD swizzle (m204)
    const int bid = blockIdx.x;
    const int q8 = nwg >> 3, r8 = nwg & 7;
    const int xcd = bid & 7, idx = bid >> 3;
    const int wgid = (xcd < r8) ? (xcd * (q8 + 1) + idx)
                                : (r8 * (q8 + 1) + (xcd - r8) * q8 + idx);
    const int rrel = wgid % R_REL;     // relation fastest -> A m-panel L2-shared
    const int mblk = wgid / R_REL;
    const int m0 = mblk * 256;

    const int tid = threadIdx.x;
    const int lane = tid & 63, wave = tid >> 6;  // 8 waves
    const int wm = wave & 1, wn = wave >> 1;     // 2M x 4N
    const int fr = lane & 15, fg = lane >> 4;

    const short* Agh = h1h + (size_t)rrel * hopStride;
    const short* Agl = h1l + (size_t)rrel * hopStride;
    const short* BTh = wch + (size_t)rrel * 256 * 768;
    const short* BTl = wcl + (size_t)rrel * 256 * 768;
    float* C = outB + (size_t)rrel * H_F;
    const float* bias = bcB + (size_t)rrel * H_F;

    // hop-phase rotation start (in k-steps of 32): r=0..4 -> 0,16,8,0,16
    const int kstart = ((3 - (rrel % 3)) % 3) * 8;

    // staging offsets: call p covers rows c*16..c*16+15 where c = wave*2+p
    int aoff[2], boff[2], loff[2];
#pragma unroll
    for (int p = 0; p < 2; ++p) {
        int c = wave * 2 + p;
        int r = c * 16 + (lane >> 2);
        int u = lane & 3;
        int g = (u - (r >> 1)) & 3;
        int ar = m0 + r; if (ar >= M) ar = M - 1;
        aoff[p] = ar * H_F + g * 8;        // A row stride 256 shorts
        boff[p] = r * 768 + g * 8;         // B row stride 768 shorts (n0 = 0)
        loff[p] = c * 512;                 // 1KB per wave-call
    }

#define STAGE_B4(buf, kg) do {                                                  \
        const short* bh_ = BTh + (kg);                                          \
        const short* bl_ = BTl + (kg);                                          \
        GLOAD16(bh_ + boff[0], &lds[buf][2][loff[0]]);                          \
        GLOAD16(bh_ + boff[1], &lds[buf][2][loff[1]]);                          \
        GLOAD16(bl_ + boff[0], &lds[buf][3][loff[0]]);                          \
        GLOAD16(bl_ + boff[1], &lds[buf][3][loff[1]]);                          \
    } while (0)

#define STAGE_A(buf, kg, p) do {                                                \
        int hop_ = (kg) >> 8, kin_ = (kg) & 255;                                \
        const short* ah_ = Agh + (size_t)hop_ * hopStride + kin_;               \
        const short* al_ = Agl + (size_t)hop_ * hopStride + kin_;               \
        GLOAD16(ah_ + aoff[p], &lds[buf][0][loff[p]]);                          \
        GLOAD16(al_ + aoff[p], &lds[buf][1][loff[p]]);                          \
    } while (0)

#define STAGE_FULL(buf, kg) do {                                                \
        STAGE_A(buf, kg, 0);                                                    \
        STAGE_A(buf, kg, 1);                                                    \
        STAGE_B4(buf, kg);                                                      \
    } while (0)

#define KIDX(t) ((((t) + kstart) % nk) * 32)

    f32x4 acc[8][4];
#pragma unroll
    for (int i = 0; i < 8; ++i)
#pragma unroll
        for (int j = 0; j < 4; ++j) acc[i][j] = (f32x4)0.f;

    const int nk = 768 / 32;  // 24
    const bool wodd = (wave & 1) != 0;

    // prologue: fill both buffers; 16 loads in flight per wave
    STAGE_FULL(0, KIDX(0));
    STAGE_FULL(1, KIDX(1));

    int cur = 0;
    for (int kt = 0; kt < nk; ++kt) {
        const bool pf = (kt + 2 < nk);
        const int kg2 = KIDX(kt + 2);

        // entry: own buf[cur] loads done; next tile's 8 stay in flight (T4)
        if (kt + 1 < nk) {
            asm volatile("s_waitcnt vmcnt(8)" ::: "memory");
        } else {
            asm volatile("s_waitcnt vmcnt(0)" ::: "memory");
        }
        __builtin_amdgcn_sched_barrier(0);
        __builtin_amdgcn_s_barrier();          // all waves' buf[cur] published
        __builtin_amdgcn_sched_barrier(0);

        const short* Ahc = &lds[cur][0][0];
        const short* Alc = &lds[cur][1][0];
        const short* Bhc = &lds[cur][2][0];
        const short* Blc = &lds[cur][3][0];

        // phase 0: B frags + mf {0,4}
        short8 bfh[4], bfl[4];
#pragma unroll
        for (int nf = 0; nf < 4; ++nf) {
            int rb = wn * 64 + nf * 16 + fr;
            int ub = (fg + (rb >> 1)) & 3;
            bfh[nf] = *(const short8*)(Bhc + rb * 32 + ub * 8);
            bfl[nf] = *(const short8*)(Blc + rb * 32 + ub * 8);
        }
        rel_phase<0, 4>(Ahc, Alc, bfh, bfl, acc, wm, fr, fg);

        // phase 1: stage B (released by phase 0) + even-wave A call 0; mf {1,5}
        if (pf) {
            STAGE_B4(cur, kg2);
            if (!wodd) STAGE_A(cur, kg2, 0);
        }
        rel_phase<1, 5>(Ahc, Alc, bfh, bfl, acc, wm, fr, fg);

        // phase 2: even-wave A call 1 (region released by phase 1); mf {2,6}
        if (pf && !wodd) STAGE_A(cur, kg2, 1);
        rel_phase<2, 6>(Ahc, Alc, bfh, bfl, acc, wm, fr, fg);

        // phase 3: odd-wave A call 0 (released by phase 2); mf {3,7}
        if (pf && wodd) STAGE_A(cur, kg2, 0);
        rel_phase<3, 7>(Ahc, Alc, bfh, bfl, acc, wm, fr, fg);

        // post: odd-wave A call 1 (released by phase 3)
        if (pf && wodd) STAGE_A(cur, kg2, 1);

        cur ^= 1;
    }

#pragma unroll
    for (int nf = 0; nf < 4; ++nf) {
        int colg = wn * 64 + nf * 16 + fr;     // n0 = 0
        float bv = bias[colg];
#pragma unroll
        for (int mf = 0; mf < 8; ++mf) {
            int rowbase = m0 + wm * 128 + mf * 16 + fg * 4;
#pragma unroll
            for (int j = 0; j < 4; ++j) {
                int rowg = rowbase + j;
                if (rowg < M)
                    C[(size_t)rowg * OUT_W + colg] = fmaxf(acc[mf][nf][j] + bv, 0.f);
            }
        }
    }
#undef STAGE_B4
#undef STAGE_A
#undef STAGE_FULL
#undef KIDX
}

// ---------------- fallback relation GEMM (pre-split A, reg-staged) ----------------
// MODE: 0 = bias, 2 = accum, 3 = accum+relu   (non-windowed path only)

template <int MODE>
__global__ __launch_bounds__(256, 2) void gemm_presplit(
    const short* __restrict__ Agh, const short* __restrict__ Agl, int lda,
    const short* __restrict__ BTh, const short* __restrict__ BTl, int ldb, int Kd,
    float* __restrict__ C, int ldc, const float* __restrict__ bias, int M)
{
    __shared__ short lds_buf[4 * 128 * LROW];
    short* Ah = lds_buf;
    short* Al = lds_buf + 128 * LROW;
    short* Bh = lds_buf + 2 * 128 * LROW;
    short* Bl = lds_buf + 3 * 128 * LROW;

    const int tid = threadIdx.x;
    const int lane = tid & 63, wave = tid >> 6;
    const int wm = wave & 1, wn = wave >> 1;
    const int fr = lane & 15, fg = lane >> 4;
    const int m0 = blockIdx.y * 128;
    const int n0 = blockIdx.x * 128;

    const int sr = tid >> 1;
    const int sc = (tid & 1) * 16;
    const bool avalid = (m0 + sr) < M;
    const int arow = avalid ? (m0 + sr) : (M - 1);

    short8 gah[2], gal[2], gbh[2], gbl[2];
    {
        const short* aph = Agh + (size_t)arow * lda + sc;
        const short* apl = Agl + (size_t)arow * lda + sc;
        const short* bph = BTh + (size_t)(n0 + sr) * ldb + sc;
        const short* bpl = BTl + (size_t)(n0 + sr) * ldb + sc;
        gah[0] = *(const short8*)aph;  gah[1] = *(const short8*)(aph + 8);
        gal[0] = *(const short8*)apl;  gal[1] = *(const short8*)(apl + 8);
        gbh[0] = *(const short8*)bph;  gbh[1] = *(const short8*)(bph + 8);
        gbl[0] = *(const short8*)bpl;  gbl[1] = *(const short8*)(bpl + 8);
    }

    f32x4 acc[4][4];
#pragma unroll
    for (int i = 0; i < 4; ++i)
#pragma unroll
        for (int j = 0; j < 4; ++j) acc[i][j] = (f32x4)0.f;

    const int nk = Kd / 32;
    for (int kk = 0; kk < nk; ++kk) {
        __syncthreads();
        *(short8*)(Ah + sr * LROW + sc)     = gah[0];
        *(short8*)(Ah + sr * LROW + sc + 8) = gah[1];
        *(short8*)(Al + sr * LROW + sc)     = gal[0];
        *(short8*)(Al + sr * LROW + sc + 8) = gal[1];
        *(short8*)(Bh + sr * LROW + sc)     = gbh[0];
        *(short8*)(Bh + sr * LROW + sc + 8) = gbh[1];
        *(short8*)(Bl + sr * LROW + sc)     = gbl[0];
        *(short8*)(Bl + sr * LROW + sc + 8) = gbl[1];
        __syncthreads();

        if (kk + 1 < nk) {
            int k0 = (kk + 1) * 32;
            const short* aph = Agh + (size_t)arow * lda + k0 + sc;
            const short* apl = Agl + (size_t)arow * lda + k0 + sc;
            const short* bph = BTh + (size_t)(n0 + sr) * ldb + k0 + sc;
            const short* bpl = BTl + (size_t)(n0 + sr) * ldb + k0 + sc;
            gah[0] = *(const short8*)aph;  gah[1] = *(const short8*)(aph + 8);
            gal[0] = *(const short8*)apl;  gal[1] = *(const short8*)(apl + 8);
            gbh[0] = *(const short8*)bph;  gbh[1] = *(const short8*)(bph + 8);
            gbl[0] = *(const short8*)bpl;  gbl[1] = *(const short8*)(bpl + 8);
        }

        short8 afh[4], afl[4], bfh[4], bfl[4];
#pragma unroll
        for (int mf = 0; mf < 4; ++mf) {
            int r = wm * 64 + mf * 16 + fr;
            afh[mf] = *(const short8*)(Ah + r * LROW + fg * 8);
            afl[mf] = *(const short8*)(Al + r * LROW + fg * 8);
        }
#pragma unroll
        for (int nf = 0; nf < 4; ++nf) {
            int r = wn * 64 + nf * 16 + fr;
            bfh[nf] = *(const short8*)(Bh + r * LROW + fg * 8);
            bfl[nf] = *(const short8*)(Bl + r * LROW + fg * 8);
        }
#pragma unroll
        for (int mf = 0; mf < 4; ++mf)
#pragma unroll
            for (int nf = 0; nf < 4; ++nf) {
                acc[mf][nf] = __builtin_amdgcn_mfma_f32_16x16x32_bf16(
                    afh[mf], bfh[nf], acc[mf][nf], 0, 0, 0);
                acc[mf][nf] = __builtin_amdgcn_mfma_f32_16x16x32_bf16(
                    afh[mf], bfl[nf], acc[mf][nf], 0, 0, 0);
                acc[mf][nf] = __builtin_amdgcn_mfma_f32_16x16x32_bf16(
                    afl[mf], bfh[nf], acc[mf][nf], 0, 0, 0);
            }
    }

#pragma unroll
    for (int nf = 0; nf < 4; ++nf) {
        int colg = n0 + wn * 64 + nf * 16 + fr;
        float bv = (MODE == 0) ? bias[colg] : 0.f;
#pragma unroll
        for (int mf = 0; mf < 4; ++mf) {
            int rowbase = m0 + wm * 64 + mf * 16 + fg * 4;
#pragma unroll
            for (int j = 0; j < 4; ++j) {
                int rowg = rowbase + j;
                if (rowg < M) {
                    size_t idx = (size_t)rowg * ldc + colg;
                    float v = acc[mf][nf][j] + bv;
                    if (MODE >= 2) v += C[idx];
                    if (MODE & 1) v = fmaxf(v, 0.f);
                    C[idx] = v;
                }
            }
        }
    }
}

// ---------------- driver ----------------

extern "C" void kernel_launch(void* const* d_in, const int* in_sizes, int n_in,
                              void* d_out, int out_size, void* d_ws, size_t ws_size,
                              hipStream_t stream) {
    const float* features = (const float*)d_in[0];
    const float* W1 = (const float*)d_in[1];
    const float* b1 = (const float*)d_in[2];
    const float* W2 = (const float*)d_in[3];
    const float* b2 = (const float*)d_in[4];
    const float* Wr = (const float*)d_in[5];
    const float* br = (const float*)d_in[6];
    const int* row = (const int*)d_in[7];
    const int* col = (const int*)d_in[8];
    float* out = (float*)d_out;

    // workspace layout (byte offsets; ws_size ~1953 MiB)
    char* ws = (char*)d_ws;
    int* deg = (int*)ws;                                 // 400KB (also cursor)
    int* rowptr = (int*)(ws + (1ull << 20));
    float* dinv = (float*)(ws + (2ull << 20));
    int* bsum = (int*)(ws + (3ull << 20));               // SCAN_B+1 ints
    int* cols2 = (int*)(ws + (4ull << 20));              // 6.4MB
    float* ew = (float*)(ws + (11ull << 20));            // 6.4MB
    short* w1h = (short*)(ws + (18ull << 20));           // 459KB
    short* w1l = (short*)(ws + (19ull << 20));
    float* wc32 = (float*)(ws + (20ull << 20));          // 3.93MB
    short* wch = (short*)(ws + (24ull << 20));           // 1.97MB
    short* wcl = (short*)(ws + (26ull << 20));
    float* bc = (float*)(ws + (28ull << 20));            // 5KB
    float* xa = (float*)(ws + (32ull << 20));            // 51.2MB
    float* xb = (float*)(ws + (96ull << 20));            // 51.2MB
    short* h1h = (short*)(ws + (160ull << 20));          // 341.8MiB (windowed)
    short* h1l = (short*)(ws + (576ull << 20));          // 341.8MiB

    const bool windowed = ws_size >= (1000ull << 20);

    // ---- adjacency normalization + CSR build ----
    zero_int<<<(N_NODES + 255) / 256, 256, 0, stream>>>(deg, N_NODES);
    deg_count<<<(E_EDGES + 255) / 256, 256, 0, stream>>>(row, deg);
    dinv_compute<<<(N_NODES + 255) / 256, 256, 0, stream>>>(deg, dinv);
    scan1<<<SCAN_B, 1024, 0, stream>>>(deg, rowptr, bsum);
    scan2<<<1, 128, 0, stream>>>(bsum);
    scan3<<<SCAN_B, 1024, 0, stream>>>(rowptr, bsum);
    zero_int<<<(N_NODES + 255) / 256, 256, 0, stream>>>(deg, N_NODES);
    csr_scatter<<<(E_EDGES + 255) / 256, 256, 0, stream>>>(row, col, dinv, rowptr,
                                                           deg, cols2, ew);

    // ---- weight fusion: Wc = W2 @ WrS, bc = br + b2 @ WrS ----
    wc_compute<<<dim3(15, 32), 256, 0, stream>>>(W2, Wr, wc32);
    bc_compute<<<R_REL, 256, 0, stream>>>(b2, Wr, br, bc);

    // ---- weight transpose + bf16 split ----
    dim3 tb(32, 8);
    transpose_convert<<<dim3(IN_F / 32, 8, K_HOPS), tb, 0, stream>>>(W1, w1h, w1l, IN_F, 1);
    transpose_convert<<<dim3(H_F / 32, 8, 15), tb, 0, stream>>>(wc32, wch, wcl, H_F, 3);

    // ---- hop loop: MLP1 (fp32 A in, split bf16 out); then propagate ----
    const float* xcur = features;
    float* bufs[2] = {xa, xb};
    for (int k = 0; k < K_HOPS; ++k) {
        short* h1hd = windowed ? (h1h + (size_t)k * N_NODES * H_F) : h1h;
        short* h1ld = windowed ? (h1l + (size_t)k * N_NODES * H_F) : h1l;
        dim3 grid(2, (N_NODES + 127) / 128);
        gemm_mlp<<<grid, 256, 0, stream>>>(xcur, w1h + (size_t)k * 256 * IN_F,
                                           w1l + (size_t)k * 256 * IN_F,
                                           h1hd, h1ld, b1 + (size_t)k * H_F, N_NODES);

        if (!windowed) {
            int rlo = (k - 2 < 0) ? 0 : (k - 2);
            int rhi = (k < R_REL - 1) ? k : (R_REL - 1);
            for (int r = rlo; r <= rhi; ++r) {
                int d = k - r;
                const short* Bh = wch + (size_t)r * 256 * 768 + (size_t)d * H_F;
                const short* Bl = wcl + (size_t)r * 256 * 768 + (size_t)d * H_F;
                float* Cp = out + (size_t)r * H_F;
                if (k == r)
                    gemm_presplit<0><<<grid, 256, 0, stream>>>(
                        h1h, h1l, H_F, Bh, Bl, 768, H_F, Cp, OUT_W,
                        bc + (size_t)r * H_F, N_NODES);
                else if (k == r + 2)
                    gemm_presplit<3><<<grid, 256, 0, stream>>>(
                        h1h, h1l, H_F, Bh, Bl, 768, H_F, Cp, OUT_W, nullptr, N_NODES);
                else
                    gemm_presplit<2><<<grid, 256, 0, stream>>>(
                        h1h, h1l, H_F, Bh, Bl, 768, H_F, Cp, OUT_W, nullptr, N_NODES);
            }
        }

        if (k < K_HOPS - 1) {
            float* xn = bufs[k & 1];
            spmm_csr<<<(N_NODES + 3) / 4, 256, 0, stream>>>(
                (const float4*)xcur, rowptr, cols2, ew, dinv, (float4*)xn);
            xcur = xn;
        }
    }

    if (windowed) {
        // all 5 relation GEMMs in one 1D launch; 256x256 tiles, rel-fastest decode
        int mblocks = (N_NODES + 255) / 256;
        int nwg = mblocks * R_REL;
        gemm_rel<<<nwg, 512, 0, stream>>>(h1h, h1l, (long)N_NODES * H_F,
                                          wch, wcl, out, bc, N_NODES, nwg);
    }
}

// Round 18
// 2019.532 us; speedup vs baseline: 2.2725x; 1.0638x over previous
//
#include <hip/hip_runtime.h>

#define N_NODES 100000
#define E_EDGES 1600000
#define IN_F 128
#define H_F 256
#define K_HOPS 7
#define R_REL 5
#define OUT_W (R_REL * H_F)  // 1280
#define SCAN_B ((N_NODES + 1023) / 1024)  // 98

typedef __attribute__((ext_vector_type(8))) short short8;
typedef __attribute__((ext_vector_type(4))) float f32x4;

// async global->LDS, 16B per lane; lds dest = base + lane*16
#define GLOAD16(g, l) __builtin_amdgcn_global_load_lds( \
    (const __attribute__((address_space(1))) void*)(g), \
    (__attribute__((address_space(3))) void*)(l), 16, 0, 0)

// ---------------- small utility kernels ----------------

__global__ void zero_int(int* __restrict__ p, int n) {
    int t = blockIdx.x * blockDim.x + threadIdx.x;
    if (t < n) p[t] = 0;
}

__global__ void deg_count(const int* __restrict__ row, int* __restrict__ deg) {
    int e = blockIdx.x * blockDim.x + threadIdx.x;
    if (e < E_EDGES) atomicAdd(&deg[row[e]], 1);
}

__global__ void dinv_compute(const int* __restrict__ deg, float* __restrict__ dinv) {
    int i = blockIdx.x * blockDim.x + threadIdx.x;
    if (i < N_NODES) dinv[i] = rsqrtf((float)(deg[i] + 1));
}

// ---- 3-pass exclusive scan of deg -> rowptr ----
__global__ __launch_bounds__(1024) void scan1(const int* __restrict__ deg,
                                              int* __restrict__ rp, int* __restrict__ bsum) {
    __shared__ int ws[16];
    const int t = threadIdx.x, lane = t & 63, wv = t >> 6;
    int i = blockIdx.x * 1024 + t;
    int v = (i < N_NODES) ? deg[i] : 0;
    int x = v;
#pragma unroll
    for (int off = 1; off < 64; off <<= 1) {
        int n = __shfl_up(x, off, 64);
        if (lane >= off) x += n;
    }
    if (lane == 63) ws[wv] = x;
    __syncthreads();
    if (wv == 0 && lane < 16) {
        int s = ws[lane];
#pragma unroll
        for (int off = 1; off < 16; off <<= 1) {
            int n = __shfl_up(s, off, 64);
            if (lane >= off) s += n;
        }
        ws[lane] = s;
    }
    __syncthreads();
    int wbase = (wv == 0) ? 0 : ws[wv - 1];
    if (i < N_NODES) rp[i] = wbase + x - v;
    if (t == 1023) bsum[blockIdx.x] = ws[15];
}

// parallel scan of the 98 block sums (one block, 128 threads = 2 waves)
__global__ __launch_bounds__(128) void scan2(int* __restrict__ bsum) {
    __shared__ int wtot[2];
    const int t = threadIdx.x, lane = t & 63, wv = t >> 6;
    int v = (t < SCAN_B) ? bsum[t] : 0;
    int x = v;
#pragma unroll
    for (int off = 1; off < 64; off <<= 1) {
        int n = __shfl_up(x, off, 64);
        if (lane >= off) x += n;
    }
    if (lane == 63) wtot[wv] = x;
    __syncthreads();
    int base = (wv == 1) ? wtot[0] : 0;
    if (t < SCAN_B) bsum[t] = base + x - v;
    if (t == 127) bsum[SCAN_B] = wtot[0] + wtot[1];
}

__global__ __launch_bounds__(1024) void scan3(int* __restrict__ rp,
                                              const int* __restrict__ bsum) {
    int i = blockIdx.x * 1024 + threadIdx.x;
    if (i < N_NODES) rp[i] += bsum[blockIdx.x];
    if (i == 0) rp[N_NODES] = bsum[SCAN_B];
}

__global__ void csr_scatter(const int* __restrict__ row, const int* __restrict__ col,
                            const float* __restrict__ dinv, const int* __restrict__ rowptr,
                            int* __restrict__ cursor, int* __restrict__ cols2,
                            float* __restrict__ ew) {
    int e = blockIdx.x * blockDim.x + threadIdx.x;
    if (e >= E_EDGES) return;
    int r = row[e], c = col[e];
    int pos = rowptr[r] + atomicAdd(&cursor[r], 1);
    cols2[pos] = c;
    ew[pos] = dinv[r] * dinv[c];
}

// y[i] = dinv[i]^2 * x[i] + sum_j w[j] * x[cols[j]]
// one wave per row; 2 edge slots x 32 lanes x float4; 4-deep unroll per slot.
__global__ __launch_bounds__(256) void spmm_csr(
    const float4* __restrict__ x, const int* __restrict__ rowptr,
    const int* __restrict__ cols, const float* __restrict__ w,
    const float* __restrict__ dinv, float4* __restrict__ y) {
    const int wave = threadIdx.x >> 6, lane = threadIdx.x & 63;
    const int i = blockIdx.x * 4 + wave;
    if (i >= N_NODES) return;
    const int fh = lane & 31;
    const int slot = lane >> 5;
    const int jb = rowptr[i];
    const int cnt = rowptr[i + 1] - jb;

    float4 acc = make_float4(0.f, 0.f, 0.f, 0.f);
    int t = slot;
    for (; t + 6 < cnt; t += 8) {
        int c0 = __builtin_nontemporal_load(&cols[jb + t]);
        int c1 = __builtin_nontemporal_load(&cols[jb + t + 2]);
        int c2 = __builtin_nontemporal_load(&cols[jb + t + 4]);
        int c3 = __builtin_nontemporal_load(&cols[jb + t + 6]);
        float ww0 = __builtin_nontemporal_load(&w[jb + t]);
        float ww1 = __builtin_nontemporal_load(&w[jb + t + 2]);
        float ww2 = __builtin_nontemporal_load(&w[jb + t + 4]);
        float ww3 = __builtin_nontemporal_load(&w[jb + t + 6]);
        float4 v0 = x[(size_t)c0 * 32 + fh];
        float4 v1 = x[(size_t)c1 * 32 + fh];
        float4 v2 = x[(size_t)c2 * 32 + fh];
        float4 v3 = x[(size_t)c3 * 32 + fh];
        acc.x += ww0 * v0.x + ww1 * v1.x + ww2 * v2.x + ww3 * v3.x;
        acc.y += ww0 * v0.y + ww1 * v1.y + ww2 * v2.y + ww3 * v3.y;
        acc.z += ww0 * v0.z + ww1 * v1.z + ww2 * v2.z + ww3 * v3.z;
        acc.w += ww0 * v0.w + ww1 * v1.w + ww2 * v2.w + ww3 * v3.w;
    }
    for (; t < cnt; t += 2) {
        int c0 = cols[jb + t];
        float ww0 = w[jb + t];
        float4 v0 = x[(size_t)c0 * 32 + fh];
        acc.x += ww0 * v0.x;
        acc.y += ww0 * v0.y;
        acc.z += ww0 * v0.z;
        acc.w += ww0 * v0.w;
    }
    acc.x += __shfl_xor(acc.x, 32);
    acc.y += __shfl_xor(acc.y, 32);
    acc.z += __shfl_xor(acc.z, 32);
    acc.w += __shfl_xor(acc.w, 32);
    if (slot == 0) {
        float d = dinv[i];
        float s = d * d;
        float4 xv = x[(size_t)i * 32 + fh];
        acc.x += s * xv.x;
        acc.y += s * xv.y;
        acc.z += s * xv.z;
        acc.w += s * xv.w;
        y[(size_t)i * 32 + fh] = acc;
    }
}

// ---------------- bf16 split helpers ----------------

__device__ __forceinline__ void f2bf_split(float v, short& h, short& l) {
    unsigned u = __float_as_uint(v);
    unsigned hb = (u + 0x7FFFu + ((u >> 16) & 1u)) >> 16;  // RN-to-even bf16
    float fh = __uint_as_float(hb << 16);
    float r = v - fh;
    unsigned u2 = __float_as_uint(r);
    unsigned lb = (u2 + 0x7FFFu + ((u2 >> 16) & 1u)) >> 16;
    h = (short)(unsigned short)hb;
    l = (short)(unsigned short)lb;
}

// ---------------- weight-fusion precompute ----------------
// Wc[z=r*3+d] = W2[r+d] @ WrS[r,d]; 8 j-rows per block via LDS A tile
__global__ __launch_bounds__(256) void wc_compute(const float* __restrict__ W2,
                                                  const float* __restrict__ Wr,
                                                  float* __restrict__ Wc) {
    __shared__ float as[8][256];
    const int z = blockIdx.x, j0 = blockIdx.y * 8, g = threadIdx.x;
    const int r = z / 3, d = z % 3, hop = r + d;
    const float* a = W2 + (size_t)hop * H_F * H_F + (size_t)j0 * H_F;
    for (int t = threadIdx.x; t < 8 * 256; t += 256)
        as[t >> 8][t & 255] = a[t];
    __syncthreads();
    const float* b = Wr + ((size_t)r * 768 + (size_t)d * H_F) * H_F + g;
    float acc[8] = {0.f, 0.f, 0.f, 0.f, 0.f, 0.f, 0.f, 0.f};
    for (int h = 0; h < H_F; ++h) {
        float bv = b[(size_t)h * H_F];
#pragma unroll
        for (int jj = 0; jj < 8; ++jj) acc[jj] += as[jj][h] * bv;
    }
#pragma unroll
    for (int jj = 0; jj < 8; ++jj)
        Wc[(size_t)z * H_F * H_F + (size_t)(j0 + jj) * H_F + g] = acc[jj];
}

// bc[r] = br[r] + sum_{d,h} b2[r+d][h] * WrS[r,d][h][:]
__global__ __launch_bounds__(256) void bc_compute(const float* __restrict__ b2,
                                                  const float* __restrict__ Wr,
                                                  const float* __restrict__ br,
                                                  float* __restrict__ bc) {
    const int r = blockIdx.x, g = threadIdx.x;
    float acc = br[(size_t)r * H_F + g];
    for (int t = 0; t < 3 * H_F; ++t) {
        float bv = b2[(size_t)(r + t / H_F) * H_F + (t % H_F)];
        acc += bv * Wr[((size_t)r * 768 + t) * H_F + g];
    }
    bc[(size_t)r * H_F + g] = acc;
}

// weight transpose+split: in [z][Kd][256] fp32 -> out group (z/grp) is [256][grp*Kd]
__global__ void transpose_convert(const float* __restrict__ in, short* __restrict__ oh,
                                  short* __restrict__ ol, int Kd, int grp) {
    __shared__ float t[32][33];
    const int i0 = blockIdx.x * 32, n0 = blockIdx.y * 32, z = blockIdx.z;
    const int tx = threadIdx.x, ty = threadIdx.y;
    const int outLd = grp * Kd;
    const float* ip = in + (size_t)z * Kd * 256;
#pragma unroll
    for (int j = 0; j < 4; ++j)
        t[ty + 8 * j][tx] = ip[(size_t)(i0 + ty + 8 * j) * 256 + n0 + tx];
    __syncthreads();
    size_t base = (size_t)(z / grp) * 256 * outLd + (size_t)(z % grp) * Kd;
#pragma unroll
    for (int j = 0; j < 4; ++j) {
        float v = t[tx][ty + 8 * j];
        short hb, lb;
        f2bf_split(v, hb, lb);
        size_t o = base + (size_t)(n0 + ty + 8 * j) * outLd + i0 + tx;
        oh[o] = hb;
        ol[o] = lb;
    }
}

// ---------------- MLP1 GEMM: fp32 A, in-kernel split, split-bf16 output ----------------
// Ch/Cl[M,256] = relu(A[M,128] @ B[128,256] + bias), reg-staged, LROW=40 pad
// Epilogue routes output through a [64][128] LDS tile (16 KB), 4 sub-passes
// (hi/lo x wm-half), so global stores are 256B-contiguous runs per row.

#define LROW 40

__global__ __launch_bounds__(256, 2) void gemm_mlp(
    const float* __restrict__ A,
    const short* __restrict__ BTh, const short* __restrict__ BTl,
    short* __restrict__ Ch, short* __restrict__ Cl,
    const float* __restrict__ bias, int M)
{
    __shared__ short lds_buf[4 * 128 * LROW];
    short* Ah = lds_buf;
    short* Al = lds_buf + 128 * LROW;
    short* Bh = lds_buf + 2 * 128 * LROW;
    short* Bl = lds_buf + 3 * 128 * LROW;

    const int tid = threadIdx.x;
    const int lane = tid & 63, wave = tid >> 6;
    const int wm = wave & 1, wn = wave >> 1;
    const int fr = lane & 15, fg = lane >> 4;
    const int m0 = blockIdx.y * 128;
    const int n0 = blockIdx.x * 128;

    const int sr = tid >> 1;
    const int sc = (tid & 1) * 16;
    const bool avalid = (m0 + sr) < M;
    const int arow = avalid ? (m0 + sr) : (M - 1);

    f32x4 ga[4];
    short8 gbh[2], gbl[2];
    {
        const float* ap = A + (size_t)arow * IN_F + sc;
        const short* bph = BTh + (size_t)(n0 + sr) * IN_F + sc;
        const short* bpl = BTl + (size_t)(n0 + sr) * IN_F + sc;
#pragma unroll
        for (int l = 0; l < 4; ++l) ga[l] = *(const f32x4*)(ap + 4 * l);
        gbh[0] = *(const short8*)bph;  gbh[1] = *(const short8*)(bph + 8);
        gbl[0] = *(const short8*)bpl;  gbl[1] = *(const short8*)(bpl + 8);
    }

    f32x4 acc[4][4];
#pragma unroll
    for (int i = 0; i < 4; ++i)
#pragma unroll
        for (int j = 0; j < 4; ++j) acc[i][j] = (f32x4)0.f;

    const int nk = IN_F / 32;  // 4
    for (int kk = 0; kk < nk; ++kk) {
        __syncthreads();
        {
            short8 vh[2], vl[2];
#pragma unroll
            for (int l = 0; l < 4; ++l) {
                f32x4 v = ga[l];
                if (!avalid) v = (f32x4)0.f;
#pragma unroll
                for (int e = 0; e < 4; ++e) {
                    short hb, lb;
                    f2bf_split(v[e], hb, lb);
                    vh[l >> 1][(l & 1) * 4 + e] = hb;
                    vl[l >> 1][(l & 1) * 4 + e] = lb;
                }
            }
            *(short8*)(Ah + sr * LROW + sc)     = vh[0];
            *(short8*)(Ah + sr * LROW + sc + 8) = vh[1];
            *(short8*)(Al + sr * LROW + sc)     = vl[0];
            *(short8*)(Al + sr * LROW + sc + 8) = vl[1];
            *(short8*)(Bh + sr * LROW + sc)     = gbh[0];
            *(short8*)(Bh + sr * LROW + sc + 8) = gbh[1];
            *(short8*)(Bl + sr * LROW + sc)     = gbl[0];
            *(short8*)(Bl + sr * LROW + sc + 8) = gbl[1];
        }
        __syncthreads();

        if (kk + 1 < nk) {
            int k0 = (kk + 1) * 32;
            const float* ap = A + (size_t)arow * IN_F + k0 + sc;
            const short* bph = BTh + (size_t)(n0 + sr) * IN_F + k0 + sc;
            const short* bpl = BTl + (size_t)(n0 + sr) * IN_F + k0 + sc;
#pragma unroll
            for (int l = 0; l < 4; ++l) ga[l] = *(const f32x4*)(ap + 4 * l);
            gbh[0] = *(const short8*)(bph);  gbh[1] = *(const short8*)(bph + 8);
            gbl[0] = *(const short8*)(bpl);  gbl[1] = *(const short8*)(bpl + 8);
        }

        short8 afh[4], afl[4], bfh[4], bfl[4];
#pragma unroll
        for (int mf = 0; mf < 4; ++mf) {
            int r = wm * 64 + mf * 16 + fr;
            afh[mf] = *(const short8*)(Ah + r * LROW + fg * 8);
            afl[mf] = *(const short8*)(Al + r * LROW + fg * 8);
        }
#pragma unroll
        for (int nf = 0; nf < 4; ++nf) {
            int r = wn * 64 + nf * 16 + fr;
            bfh[nf] = *(const short8*)(Bh + r * LROW + fg * 8);
            bfl[nf] = *(const short8*)(Bl + r * LROW + fg * 8);
        }
#pragma unroll
        for (int mf = 0; mf < 4; ++mf)
#pragma unroll
            for (int nf = 0; nf < 4; ++nf) {
                acc[mf][nf] = __builtin_amdgcn_mfma_f32_16x16x32_bf16(
                    afh[mf], bfh[nf], acc[mf][nf], 0, 0, 0);
                acc[mf][nf] = __builtin_amdgcn_mfma_f32_16x16x32_bf16(
                    afh[mf], bfl[nf], acc[mf][nf], 0, 0, 0);
                acc[mf][nf] = __builtin_amdgcn_mfma_f32_16x16x32_bf16(
                    afl[mf], bfh[nf], acc[mf][nf], 0, 0, 0);
            }
    }

    // ---- epilogue: relu+bias, split, then LDS-staged coalesced store ----
    short hfrag[4][4][4], lfrag[4][4][4];
#pragma unroll
    for (int nf = 0; nf < 4; ++nf) {
        int colg = n0 + wn * 64 + nf * 16 + fr;
        float bv = bias[colg];
#pragma unroll
        for (int mf = 0; mf < 4; ++mf)
#pragma unroll
            for (int j = 0; j < 4; ++j) {
                float v = fmaxf(acc[mf][nf][j] + bv, 0.f);
                f2bf_split(v, hfrag[mf][nf][j], lfrag[mf][nf][j]);
            }
    }
    __syncthreads();  // K-loop LDS reads done on all waves; buf now reusable

    // staging tile: [64 rows][128 cols] shorts = 16 KB.
    // deposit cols: wn*64 + nf*16 + fr  (wn in {0,1}) -> exactly [0,128).
    // copy-out: this block's n-half only (global cols n0..n0+127).
    short* ldsS = lds_buf;
    const int crow = tid >> 2;            // 0..63
    const int cchk = (tid & 3) * 32;      // 32-short chunk within the 128-col tile
#pragma unroll
    for (int half = 0; half < 2; ++half) {     // wm-half: rows m0+half*64 ..
#pragma unroll
        for (int hl = 0; hl < 2; ++hl) {       // 0 = hi, 1 = lo
            if (wm == half) {
#pragma unroll
                for (int nf = 0; nf < 4; ++nf) {
                    int col = wn * 64 + nf * 16 + fr;   // 0..127
#pragma unroll
                    for (int mf = 0; mf < 4; ++mf) {
                        int rl = mf * 16 + fg * 4;      // local row base 0..63
#pragma unroll
                        for (int j = 0; j < 4; ++j)
                            ldsS[(rl + j) * 128 + col] =
                                hl ? lfrag[mf][nf][j] : hfrag[mf][nf][j];
                    }
                }
            }
            __syncthreads();
            {
                int rowg = m0 + half * 64 + crow;
                if (rowg < M) {
                    short* dst = (hl ? Cl : Ch) + (size_t)rowg * H_F + n0 + cchk;
                    const short* src = ldsS + crow * 128 + cchk;
                    *(short8*)(dst)      = *(const short8*)(src);
                    *(short8*)(dst + 8)  = *(const short8*)(src + 8);
                    *(short8*)(dst + 16) = *(const short8*)(src + 16);
                    *(short8*)(dst + 24) = *(const short8*)(src + 24);
                }
            }
            __syncthreads();
        }
    }
}

// ---------------- relation GEMM v6: 256x256, 4-phase/K-step interleave (T3+T4) ----
// (unchanged from round 16 — best known: ~678 us, MfmaUtil 37)

__device__ __forceinline__ f32x4 mfma16(short8 a, short8 b, f32x4 c) {
    return __builtin_amdgcn_mfma_f32_16x16x32_bf16(a, b, c, 0, 0, 0);
}

template <int MFA, int MFB>
__device__ __forceinline__ void rel_phase(
    const short* Ahc, const short* Alc,
    const short8* bfh, const short8* bfl,
    f32x4 (&acc)[8][4], int wm, int fr, int fg)
{
    const int ra0 = wm * 128 + MFA * 16 + fr;
    const int ua0 = (fg + (ra0 >> 1)) & 3;
    short8 ahA = *(const short8*)(Ahc + ra0 * 32 + ua0 * 8);
    short8 alA = *(const short8*)(Alc + ra0 * 32 + ua0 * 8);
    const int ra1 = wm * 128 + MFB * 16 + fr;
    const int ua1 = (fg + (ra1 >> 1)) & 3;
    short8 ahB = *(const short8*)(Ahc + ra1 * 32 + ua1 * 8);
    short8 alB = *(const short8*)(Alc + ra1 * 32 + ua1 * 8);
    __builtin_amdgcn_sched_barrier(0);
    __builtin_amdgcn_s_barrier();
    asm volatile("s_waitcnt lgkmcnt(0)" ::: "memory");
    __builtin_amdgcn_sched_barrier(0);
    __builtin_amdgcn_s_setprio(1);
#pragma unroll
    for (int nf = 0; nf < 4; ++nf) {
        acc[MFA][nf] = mfma16(ahA, bfh[nf], acc[MFA][nf]);
        acc[MFA][nf] = mfma16(ahA, bfl[nf], acc[MFA][nf]);
        acc[MFA][nf] = mfma16(alA, bfh[nf], acc[MFA][nf]);
        acc[MFB][nf] = mfma16(ahB, bfh[nf], acc[MFB][nf]);
        acc[MFB][nf] = mfma16(ahB, bfl[nf], acc[MFB][nf]);
        acc[MFB][nf] = mfma16(alB, bfh[nf], acc[MFB][nf]);
    }
    __builtin_amdgcn_s_setprio(0);
    __builtin_amdgcn_sched_barrier(0);
    __builtin_amdgcn_s_barrier();
    __builtin_amdgcn_sched_barrier(0);
}

__global__ __launch_bounds__(512, 2) void gemm_rel(
    const short* __restrict__ h1h, const short* __restrict__ h1l, long hopStride,
    const short* __restrict__ wch, const short* __restrict__ wcl,
    float* __restrict__ outB, const float* __restrict__ bcB, int M, int nwg)
{
    __shared__ short lds[2][4][8192];  // Ah, Al, Bh, Bl: 256 rows x 32 k each

    // bijective XCD swizzle (m204)
    const int bid = blockIdx.x;
    const int q8 = nwg >> 3, r8 = nwg & 7;
    const int xcd = bid & 7, idx = bid >> 3;
    const int wgid = (xcd < r8) ? (xcd * (q8 + 1) + idx)
                                : (r8 * (q8 + 1) + (xcd - r8) * q8 + idx);
    const int rrel = wgid % R_REL;     // relation fastest -> A m-panel L2-shared
    const int mblk = wgid / R_REL;
    const int m0 = mblk * 256;

    const int tid = threadIdx.x;
    const int lane = tid & 63, wave = tid >> 6;  // 8 waves
    const int wm = wave & 1, wn = wave >> 1;     // 2M x 4N
    const int fr = lane & 15, fg = lane >> 4;

    const short* Agh = h1h + (size_t)rrel * hopStride;
    const short* Agl = h1l + (size_t)rrel * hopStride;
    const short* BTh = wch + (size_t)rrel * 256 * 768;
    const short* BTl = wcl + (size_t)rrel * 256 * 768;
    float* C = outB + (size_t)rrel * H_F;
    const float* bias = bcB + (size_t)rrel * H_F;

    // hop-phase rotation start (in k-steps of 32): r=0..4 -> 0,16,8,0,16
    const int kstart = ((3 - (rrel % 3)) % 3) * 8;

    // staging offsets: call p covers rows c*16..c*16+15 where c = wave*2+p
    int aoff[2], boff[2], loff[2];
#pragma unroll
    for (int p = 0; p < 2; ++p) {
        int c = wave * 2 + p;
        int r = c * 16 + (lane >> 2);
        int u = lane & 3;
        int g = (u - (r >> 1)) & 3;
        int ar = m0 + r; if (ar >= M) ar = M - 1;
        aoff[p] = ar * H_F + g * 8;        // A row stride 256 shorts
        boff[p] = r * 768 + g * 8;         // B row stride 768 shorts (n0 = 0)
        loff[p] = c * 512;                 // 1KB per wave-call
    }

#define STAGE_B4(buf, kg) do {                                                  \
        const short* bh_ = BTh + (kg);                                          \
        const short* bl_ = BTl + (kg);                                          \
        GLOAD16(bh_ + boff[0], &lds[buf][2][loff[0]]);                          \
        GLOAD16(bh_ + boff[1], &lds[buf][2][loff[1]]);                          \
        GLOAD16(bl_ + boff[0], &lds[buf][3][loff[0]]);                          \
        GLOAD16(bl_ + boff[1], &lds[buf][3][loff[1]]);                          \
    } while (0)

#define STAGE_A(buf, kg, p) do {                                                \
        int hop_ = (kg) >> 8, kin_ = (kg) & 255;                                \
        const short* ah_ = Agh + (size_t)hop_ * hopStride + kin_;               \
        const short* al_ = Agl + (size_t)hop_ * hopStride + kin_;               \
        GLOAD16(ah_ + aoff[p], &lds[buf][0][loff[p]]);                          \
        GLOAD16(al_ + aoff[p], &lds[buf][1][loff[p]]);                          \
    } while (0)

#define STAGE_FULL(buf, kg) do {                                                \
        STAGE_A(buf, kg, 0);                                                    \
        STAGE_A(buf, kg, 1);                                                    \
        STAGE_B4(buf, kg);                                                      \
    } while (0)

#define KIDX(t) ((((t) + kstart) % nk) * 32)

    f32x4 acc[8][4];
#pragma unroll
    for (int i = 0; i < 8; ++i)
#pragma unroll
        for (int j = 0; j < 4; ++j) acc[i][j] = (f32x4)0.f;

    const int nk = 768 / 32;  // 24
    const bool wodd = (wave & 1) != 0;

    // prologue: fill both buffers; 16 loads in flight per wave
    STAGE_FULL(0, KIDX(0));
    STAGE_FULL(1, KIDX(1));

    int cur = 0;
    for (int kt = 0; kt < nk; ++kt) {
        const bool pf = (kt + 2 < nk);
        const int kg2 = KIDX(kt + 2);

        // entry: own buf[cur] loads done; next tile's 8 stay in flight (T4)
        if (kt + 1 < nk) {
            asm volatile("s_waitcnt vmcnt(8)" ::: "memory");
        } else {
            asm volatile("s_waitcnt vmcnt(0)" ::: "memory");
        }
        __builtin_amdgcn_sched_barrier(0);
        __builtin_amdgcn_s_barrier();          // all waves' buf[cur] published
        __builtin_amdgcn_sched_barrier(0);

        const short* Ahc = &lds[cur][0][0];
        const short* Alc = &lds[cur][1][0];
        const short* Bhc = &lds[cur][2][0];
        const short* Blc = &lds[cur][3][0];

        // phase 0: B frags + mf {0,4}
        short8 bfh[4], bfl[4];
#pragma unroll
        for (int nf = 0; nf < 4; ++nf) {
            int rb = wn * 64 + nf * 16 + fr;
            int ub = (fg + (rb >> 1)) & 3;
            bfh[nf] = *(const short8*)(Bhc + rb * 32 + ub * 8);
            bfl[nf] = *(const short8*)(Blc + rb * 32 + ub * 8);
        }
        rel_phase<0, 4>(Ahc, Alc, bfh, bfl, acc, wm, fr, fg);

        // phase 1: stage B (released by phase 0) + even-wave A call 0; mf {1,5}
        if (pf) {
            STAGE_B4(cur, kg2);
            if (!wodd) STAGE_A(cur, kg2, 0);
        }
        rel_phase<1, 5>(Ahc, Alc, bfh, bfl, acc, wm, fr, fg);

        // phase 2: even-wave A call 1 (region released by phase 1); mf {2,6}
        if (pf && !wodd) STAGE_A(cur, kg2, 1);
        rel_phase<2, 6>(Ahc, Alc, bfh, bfl, acc, wm, fr, fg);

        // phase 3: odd-wave A call 0 (released by phase 2); mf {3,7}
        if (pf && wodd) STAGE_A(cur, kg2, 0);
        rel_phase<3, 7>(Ahc, Alc, bfh, bfl, acc, wm, fr, fg);

        // post: odd-wave A call 1 (released by phase 3)
        if (pf && wodd) STAGE_A(cur, kg2, 1);

        cur ^= 1;
    }

#pragma unroll
    for (int nf = 0; nf < 4; ++nf) {
        int colg = wn * 64 + nf * 16 + fr;     // n0 = 0
        float bv = bias[colg];
#pragma unroll
        for (int mf = 0; mf < 8; ++mf) {
            int rowbase = m0 + wm * 128 + mf * 16 + fg * 4;
#pragma unroll
            for (int j = 0; j < 4; ++j) {
                int rowg = rowbase + j;
                if (rowg < M)
                    C[(size_t)rowg * OUT_W + colg] = fmaxf(acc[mf][nf][j] + bv, 0.f);
            }
        }
    }
#undef STAGE_B4
#undef STAGE_A
#undef STAGE_FULL
#undef KIDX
}

// ---------------- fallback relation GEMM (pre-split A, reg-staged) ----------------
// MODE: 0 = bias, 2 = accum, 3 = accum+relu   (non-windowed path only)

template <int MODE>
__global__ __launch_bounds__(256, 2) void gemm_presplit(
    const short* __restrict__ Agh, const short* __restrict__ Agl, int lda,
    const short* __restrict__ BTh, const short* __restrict__ BTl, int ldb, int Kd,
    float* __restrict__ C, int ldc, const float* __restrict__ bias, int M)
{
    __shared__ short lds_buf[4 * 128 * LROW];
    short* Ah = lds_buf;
    short* Al = lds_buf + 128 * LROW;
    short* Bh = lds_buf + 2 * 128 * LROW;
    short* Bl = lds_buf + 3 * 128 * LROW;

    const int tid = threadIdx.x;
    const int lane = tid & 63, wave = tid >> 6;
    const int wm = wave & 1, wn = wave >> 1;
    const int fr = lane & 15, fg = lane >> 4;
    const int m0 = blockIdx.y * 128;
    const int n0 = blockIdx.x * 128;

    const int sr = tid >> 1;
    const int sc = (tid & 1) * 16;
    const bool avalid = (m0 + sr) < M;
    const int arow = avalid ? (m0 + sr) : (M - 1);

    short8 gah[2], gal[2], gbh[2], gbl[2];
    {
        const short* aph = Agh + (size_t)arow * lda + sc;
        const short* apl = Agl + (size_t)arow * lda + sc;
        const short* bph = BTh + (size_t)(n0 + sr) * ldb + sc;
        const short* bpl = BTl + (size_t)(n0 + sr) * ldb + sc;
        gah[0] = *(const short8*)aph;  gah[1] = *(const short8*)(aph + 8);
        gal[0] = *(const short8*)apl;  gal[1] = *(const short8*)(apl + 8);
        gbh[0] = *(const short8*)bph;  gbh[1] = *(const short8*)(bph + 8);
        gbl[0] = *(const short8*)bpl;  gbl[1] = *(const short8*)(bpl + 8);
    }

    f32x4 acc[4][4];
#pragma unroll
    for (int i = 0; i < 4; ++i)
#pragma unroll
        for (int j = 0; j < 4; ++j) acc[i][j] = (f32x4)0.f;

    const int nk = Kd / 32;
    for (int kk = 0; kk < nk; ++kk) {
        __syncthreads();
        *(short8*)(Ah + sr * LROW + sc)     = gah[0];
        *(short8*)(Ah + sr * LROW + sc + 8) = gah[1];
        *(short8*)(Al + sr * LROW + sc)     = gal[0];
        *(short8*)(Al + sr * LROW + sc + 8) = gal[1];
        *(short8*)(Bh + sr * LROW + sc)     = gbh[0];
        *(short8*)(Bh + sr * LROW + sc + 8) = gbh[1];
        *(short8*)(Bl + sr * LROW + sc)     = gbl[0];
        *(short8*)(Bl + sr * LROW + sc + 8) = gbl[1];
        __syncthreads();

        if (kk + 1 < nk) {
            int k0 = (kk + 1) * 32;
            const short* aph = Agh + (size_t)arow * lda + k0 + sc;
            const short* apl = Agl + (size_t)arow * lda + k0 + sc;
            const short* bph = BTh + (size_t)(n0 + sr) * ldb + k0 + sc;
            const short* bpl = BTl + (size_t)(n0 + sr) * ldb + k0 + sc;
            gah[0] = *(const short8*)aph;  gah[1] = *(const short8*)(aph + 8);
            gal[0] = *(const short8*)apl;  gal[1] = *(const short8*)(apl + 8);
            gbh[0] = *(const short8*)bph;  gbh[1] = *(const short8*)(bph + 8);
            gbl[0] = *(const short8*)bpl;  gbl[1] = *(const short8*)(bpl + 8);
        }

        short8 afh[4], afl[4], bfh[4], bfl[4];
#pragma unroll
        for (int mf = 0; mf < 4; ++mf) {
            int r = wm * 64 + mf * 16 + fr;
            afh[mf] = *(const short8*)(Ah + r * LROW + fg * 8);
            afl[mf] = *(const short8*)(Al + r * LROW + fg * 8);
        }
#pragma unroll
        for (int nf = 0; nf < 4; ++nf) {
            int r = wn * 64 + nf * 16 + fr;
            bfh[nf] = *(const short8*)(Bh + r * LROW + fg * 8);
            bfl[nf] = *(const short8*)(Bl + r * LROW + fg * 8);
        }
#pragma unroll
        for (int mf = 0; mf < 4; ++mf)
#pragma unroll
            for (int nf = 0; nf < 4; ++nf) {
                acc[mf][nf] = __builtin_amdgcn_mfma_f32_16x16x32_bf16(
                    afh[mf], bfh[nf], acc[mf][nf], 0, 0, 0);
                acc[mf][nf] = __builtin_amdgcn_mfma_f32_16x16x32_bf16(
                    afh[mf], bfl[nf], acc[mf][nf], 0, 0, 0);
                acc[mf][nf] = __builtin_amdgcn_mfma_f32_16x16x32_bf16(
                    afl[mf], bfh[nf], acc[mf][nf], 0, 0, 0);
            }
    }

#pragma unroll
    for (int nf = 0; nf < 4; ++nf) {
        int colg = n0 + wn * 64 + nf * 16 + fr;
        float bv = (MODE == 0) ? bias[colg] : 0.f;
#pragma unroll
        for (int mf = 0; mf < 4; ++mf) {
            int rowbase = m0 + wm * 64 + mf * 16 + fg * 4;
#pragma unroll
            for (int j = 0; j < 4; ++j) {
                int rowg = rowbase + j;
                if (rowg < M) {
                    size_t idx = (size_t)rowg * ldc + colg;
                    float v = acc[mf][nf][j] + bv;
                    if (MODE >= 2) v += C[idx];
                    if (MODE & 1) v = fmaxf(v, 0.f);
                    C[idx] = v;
                }
            }
        }
    }
}

// ---------------- driver ----------------

extern "C" void kernel_launch(void* const* d_in, const int* in_sizes, int n_in,
                              void* d_out, int out_size, void* d_ws, size_t ws_size,
                              hipStream_t stream) {
    const float* features = (const float*)d_in[0];
    const float* W1 = (const float*)d_in[1];
    const float* b1 = (const float*)d_in[2];
    const float* W2 = (const float*)d_in[3];
    const float* b2 = (const float*)d_in[4];
    const float* Wr = (const float*)d_in[5];
    const float* br = (const float*)d_in[6];
    const int* row = (const int*)d_in[7];
    const int* col = (const int*)d_in[8];
    float* out = (float*)d_out;

    // workspace layout (byte offsets; ws_size ~1953 MiB)
    char* ws = (char*)d_ws;
    int* deg = (int*)ws;                                 // 400KB (also cursor)
    int* rowptr = (int*)(ws + (1ull << 20));
    float* dinv = (float*)(ws + (2ull << 20));
    int* bsum = (int*)(ws + (3ull << 20));               // SCAN_B+1 ints
    int* cols2 = (int*)(ws + (4ull << 20));              // 6.4MB
    float* ew = (float*)(ws + (11ull << 20));            // 6.4MB
    short* w1h = (short*)(ws + (18ull << 20));           // 459KB
    short* w1l = (short*)(ws + (19ull << 20));
    float* wc32 = (float*)(ws + (20ull << 20));          // 3.93MB
    short* wch = (short*)(ws + (24ull << 20));           // 1.97MB
    short* wcl = (short*)(ws + (26ull << 20));
    float* bc = (float*)(ws + (28ull << 20));            // 5KB
    float* xa = (float*)(ws + (32ull << 20));            // 51.2MB
    float* xb = (float*)(ws + (96ull << 20));            // 51.2MB
    short* h1h = (short*)(ws + (160ull << 20));          // 341.8MiB (windowed)
    short* h1l = (short*)(ws + (576ull << 20));          // 341.8MiB

    const bool windowed = ws_size >= (1000ull << 20);

    // ---- adjacency normalization + CSR build ----
    zero_int<<<(N_NODES + 255) / 256, 256, 0, stream>>>(deg, N_NODES);
    deg_count<<<(E_EDGES + 255) / 256, 256, 0, stream>>>(row, deg);
    dinv_compute<<<(N_NODES + 255) / 256, 256, 0, stream>>>(deg, dinv);
    scan1<<<SCAN_B, 1024, 0, stream>>>(deg, rowptr, bsum);
    scan2<<<1, 128, 0, stream>>>(bsum);
    scan3<<<SCAN_B, 1024, 0, stream>>>(rowptr, bsum);
    zero_int<<<(N_NODES + 255) / 256, 256, 0, stream>>>(deg, N_NODES);
    csr_scatter<<<(E_EDGES + 255) / 256, 256, 0, stream>>>(row, col, dinv, rowptr,
                                                           deg, cols2, ew);

    // ---- weight fusion: Wc = W2 @ WrS, bc = br + b2 @ WrS ----
    wc_compute<<<dim3(15, 32), 256, 0, stream>>>(W2, Wr, wc32);
    bc_compute<<<R_REL, 256, 0, stream>>>(b2, Wr, br, bc);

    // ---- weight transpose + bf16 split ----
    dim3 tb(32, 8);
    transpose_convert<<<dim3(IN_F / 32, 8, K_HOPS), tb, 0, stream>>>(W1, w1h, w1l, IN_F, 1);
    transpose_convert<<<dim3(H_F / 32, 8, 15), tb, 0, stream>>>(wc32, wch, wcl, H_F, 3);

    // ---- hop loop: MLP1 (fp32 A in, split bf16 out); then propagate ----
    const float* xcur = features;
    float* bufs[2] = {xa, xb};
    for (int k = 0; k < K_HOPS; ++k) {
        short* h1hd = windowed ? (h1h + (size_t)k * N_NODES * H_F) : h1h;
        short* h1ld = windowed ? (h1l + (size_t)k * N_NODES * H_F) : h1l;
        dim3 grid(2, (N_NODES + 127) / 128);
        gemm_mlp<<<grid, 256, 0, stream>>>(xcur, w1h + (size_t)k * 256 * IN_F,
                                           w1l + (size_t)k * 256 * IN_F,
                                           h1hd, h1ld, b1 + (size_t)k * H_F, N_NODES);

        if (!windowed) {
            int rlo = (k - 2 < 0) ? 0 : (k - 2);
            int rhi = (k < R_REL - 1) ? k : (R_REL - 1);
            for (int r = rlo; r <= rhi; ++r) {
                int d = k - r;
                const short* Bh = wch + (size_t)r * 256 * 768 + (size_t)d * H_F;
                const short* Bl = wcl + (size_t)r * 256 * 768 + (size_t)d * H_F;
                float* Cp = out + (size_t)r * H_F;
                if (k == r)
                    gemm_presplit<0><<<grid, 256, 0, stream>>>(
                        h1h, h1l, H_F, Bh, Bl, 768, H_F, Cp, OUT_W,
                        bc + (size_t)r * H_F, N_NODES);
                else if (k == r + 2)
                    gemm_presplit<3><<<grid, 256, 0, stream>>>(
                        h1h, h1l, H_F, Bh, Bl, 768, H_F, Cp, OUT_W, nullptr, N_NODES);
                else
                    gemm_presplit<2><<<grid, 256, 0, stream>>>(
                        h1h, h1l, H_F, Bh, Bl, 768, H_F, Cp, OUT_W, nullptr, N_NODES);
            }
        }

        if (k < K_HOPS - 1) {
            float* xn = bufs[k & 1];
            spmm_csr<<<(N_NODES + 3) / 4, 256, 0, stream>>>(
                (const float4*)xcur, rowptr, cols2, ew, dinv, (float4*)xn);
            xcur = xn;
        }
    }

    if (windowed) {
        // all 5 relation GEMMs in one 1D launch; 256x256 tiles, rel-fastest decode
        int mblocks = (N_NODES + 255) / 256;
        int nwg = mblocks * R_REL;
        gemm_rel<<<nwg, 512, 0, stream>>>(h1h, h1l, (long)N_NODES * H_F,
                                          wch, wcl, out, bc, N_NODES, nwg);
    }
}